// Round 10
// baseline (1621.206 us; speedup 1.0000x reference)
//
#include <hip/hip_runtime.h>
#include <hip/hip_bf16.h>
#include <hip/hip_fp16.h>
#include <math.h>

#define NNODES 50000
#define NEDGES 800000

// ---------------- workspace layout (bytes) ----------------
#define OFF_CW       0ull                      // u64[50000] packed count|w_in (zeroed)
#define OFF_DOUT     401408ull                 // int[50000] (zeroed)
#define OFF_STATS2   602112ull                 // float[2*512] (zeroed)
#define OFF_SP8      606208ull                 // float[11*16*512] (zeroed)
#define OFF_MOM      966656ull                 // float[16*800] (zeroed)
#define ZERO_END     1017856ull
#define OFF_ST       1017856ull                // float[512]
#define OFF_ABW      1019904ull                // float[1536]: bb[512]|ww[512]|g32[32]|cb
#define OFF_WIN      1026048ull                // float[50000]
#define OFF_OFFSETS  1226752ull                // int[50001]
#define OFF_SE       1427456ull                // int2[800000] packed (srow, ew)
#define OFF_RANK     7827456ull                // int[800000]; aliased after scatter:
#define ALI_WT2      0ull                      //   ushort[256*256] (later Wp2)
#define ALI_BIAS2    131072ull                 //   float[256]
#define ALI_G        132096ull                 //   float2[50000]
#define OFF_WT       11027456ull               // ushort[10*256*256] fp16 W (transposed)
#define OFF_BUFQ     12371968ull               // half[50000*256]
#define OFF_BUFP     37971968ull               // half[50000*256]
// aliases inside dead BUFQ (after 10th spmm; agg2 dead before 1st gemm):
#define ALI_TMP16    0ull                      // float[50000*16]
#define ALI_HRAW     3276800ull                // float[50000*16]
#define ALI_Z        6553600ull                // ushort[50000*16]
#define ALI_AGGZ     8388608ull                // float[50000*16]

typedef __attribute__((ext_vector_type(8))) _Float16 f16x8;
typedef __attribute__((ext_vector_type(4))) float f32x4;

union H4 { ushort4 u; __half h[4]; };
union US8 { uint4 u; __half h[8]; };
union HU { ushort u; __half h; };

static __device__ inline ushort f2h(float f) {
    HU cv; cv.h = __float2half(f); return cv.u;
}
static __device__ inline float h2f(ushort u) {
    HU cv; cv.u = u; return __half2float(cv.h);
}

// ---------------- preprocessing ----------------

__global__ void hist_kernel(const int* __restrict__ ei, const float* __restrict__ ew,
                            unsigned long long* __restrict__ cw, int* __restrict__ dout,
                            int* __restrict__ rank, int E) {
    for (int i = blockIdx.x * blockDim.x + threadIdx.x; i < E; i += gridDim.x * blockDim.x) {
        int r = ei[i];
        int c = ei[E + i];
        unsigned long long pack = (1ull << 40) |
            (unsigned long long)__float2uint_rn(ew[i] * 1048576.f);
        unsigned long long old = atomicAdd(&cw[c], pack);
        rank[i] = (int)(old >> 40);
        atomicAdd(&dout[r], 1);
    }
}

__global__ void scan_kernel(const unsigned long long* __restrict__ cw,
                            int* __restrict__ offsets, float* __restrict__ w_in, int N) {
    __shared__ int wsum[16];
    __shared__ int carry_s;
    int tid = threadIdx.x;
    int lane = tid & 63, w = tid >> 6;
    if (tid == 0) carry_s = 0;
    __syncthreads();
    for (int base = 0; base < N; base += 1024) {
        int v = 0;
        if (base + tid < N) {
            unsigned long long cv = cw[base + tid];
            v = (int)(cv >> 40);
            w_in[base + tid] = (float)(cv & 0xFFFFFFFFFFull) * (1.f / 1048576.f);
        }
        int x = v;
#pragma unroll
        for (int off = 1; off < 64; off <<= 1) {
            int y = __shfl_up(x, off);
            if (lane >= off) x += y;
        }
        if (lane == 63) wsum[w] = x;
        __syncthreads();
        if (w == 0 && lane < 16) {
            int s = wsum[lane];
#pragma unroll
            for (int off = 1; off < 16; off <<= 1) {
                int y = __shfl_up(s, off);
                if (lane >= off) s += y;
            }
            wsum[lane] = s;
        }
        __syncthreads();
        int wbase = (w > 0) ? wsum[w - 1] : 0;
        int incl = carry_s + wbase + x;
        if (base + tid < N) offsets[base + tid] = incl - v;
        __syncthreads();
        if (tid == 0) carry_s += wsum[15];
        __syncthreads();
    }
    if (tid == 0) offsets[N] = carry_s;
}

__global__ void scatter_kernel(const int* __restrict__ ei, const float* __restrict__ ew,
                               const int* __restrict__ offsets, const int* __restrict__ rank,
                               int2* __restrict__ se, int E) {
    for (int i = blockIdx.x * blockDim.x + threadIdx.x; i < E; i += gridDim.x * blockDim.x) {
        int c = ei[E + i];
        int p = offsets[c] + rank[i];
        se[p] = make_int2(ei[i], __float_as_int(ew[i]));
    }
}

// ---------------- weight preconvert: Wt[n][k] = fp16(Wm[k][n]) ----------------

__global__ __launch_bounds__(256) void wconv(const float* __restrict__ Wm,
                                             ushort* __restrict__ Wt) {
    __shared__ float tile[32][33];
    int b = blockIdx.x;
    int layer = b >> 6, t = b & 63;
    int tk = (t >> 3) << 5, tn = (t & 7) << 5;
    int tid = threadIdx.x;
    int r = tid >> 5, c = tid & 31;
    const float* W = Wm + layer * 65536;
#pragma unroll
    for (int i = 0; i < 4; i++) tile[r + i * 8][c] = W[(tk + r + i * 8) * 256 + tn + c];
    __syncthreads();
#pragma unroll
    for (int i = 0; i < 4; i++) {
        int n = tn + r + i * 8, k = tk + c;
        Wt[layer * 65536 + n * 256 + k] = f2h(tile[c][r + i * 8]);
    }
}

// ---------------- small-C column stats (wave-reduced) ----------------

__global__ __launch_bounds__(256) void colstats_wr(const float* __restrict__ h,
                                                   float* __restrict__ sums, int C, int M) {
    int gtid = blockIdx.x * blockDim.x + threadIdx.x;
    int lane = threadIdx.x & 63;
    int c = gtid % C;
    int r = gtid / C;
    int stride = (gridDim.x * blockDim.x) / C;
    float s = 0.f, q = 0.f;
    for (; r < M; r += stride) {
        float v = h[r * C + c];
        s += v; q += v * v;
    }
    for (int m = 32; m >= C; m >>= 1) {
        s += __shfl_xor(s, m);
        q += __shfl_xor(q, m);
    }
    if (lane < C) {
        atomicAdd(&sums[c], s);
        atomicAdd(&sums[C + c], q);
    }
}

__global__ void bn_finalize(const float* __restrict__ sums, const float* __restrict__ g,
                            const float* __restrict__ b, float* __restrict__ st, int C, int M) {
    int c = threadIdx.x;
    if (c >= C) return;
    float mean = sums[c] / (float)M;
    float var  = sums[C + c] / (float)M - mean * mean;
    float sc = g[c] * rsqrtf(var + 1e-5f);
    st[c] = sc;
    st[C + c] = b[c] - mean * sc;
}

__global__ void bn_finalize16(const float* __restrict__ sp, const float* __restrict__ g,
                              const float* __restrict__ b, float* __restrict__ st, int M) {
    int c = threadIdx.x;
    float s = 0.f, q = 0.f;
#pragma unroll
    for (int p = 0; p < 16; p++) { s += sp[p * 512 + c]; q += sp[p * 512 + 256 + c]; }
    float mean = s / (float)M;
    float var  = q / (float)M - mean * mean;
    float sc = g[c] * rsqrtf(var + 1e-5f);
    st[c] = sc;
    st[256 + c] = b[c] - mean * sc;
}

// ---------------- per-layer weight fold: Wt2 = s∘Wt (fp16), bias2 = bias + t@W ----------------

__global__ __launch_bounds__(256) void bnw(const float* __restrict__ sp,
                                           const float* __restrict__ g,
                                           const float* __restrict__ b,
                                           const ushort* __restrict__ Wt,
                                           const float* __restrict__ bias,
                                           ushort* __restrict__ Wt2,
                                           float* __restrict__ bias2, int M) {
    __shared__ float st_s[512];
    int tid = threadIdx.x;
    {
        float s = 0.f, q = 0.f;
#pragma unroll
        for (int p = 0; p < 16; p++) { s += sp[p * 512 + tid]; q += sp[p * 512 + 256 + tid]; }
        float invM = 1.f / (float)M;
        float mean = s * invM;
        float var  = q * invM - mean * mean;
        float sc = g[tid] * rsqrtf(var + 1e-5f);
        st_s[tid] = sc;
        st_s[256 + tid] = b[tid] - mean * sc;
    }
    __syncthreads();
    int n = blockIdx.x * 4 + (tid >> 6);
    int k4 = (tid & 63) << 2;
    ushort4 w4 = *(const ushort4*)(Wt + n * 256 + k4);
    float4 s4 = *(const float4*)(st_s + k4);
    float4 t4 = *(const float4*)(st_s + 256 + k4);
    float w0 = h2f(w4.x), w1 = h2f(w4.y), w2 = h2f(w4.z), w3 = h2f(w4.w);
    ushort4 o;
    o.x = f2h(w0 * s4.x); o.y = f2h(w1 * s4.y);
    o.z = f2h(w2 * s4.z); o.w = f2h(w3 * s4.w);
    *(ushort4*)(Wt2 + n * 256 + k4) = o;
    float part = w0 * t4.x + w1 * t4.y + w2 * t4.z + w3 * t4.w;
#pragma unroll
    for (int m = 1; m < 64; m <<= 1) part += __shfl_xor(part, m);
    if ((tid & 63) == 0) bias2[n] = bias[n] + part;
}

// ---------------- MFMA GEMM (fp16, full 256-wide N): out = H@Wt2 + bias2 ----------------
// acc[2][16] (128 VGPR); A-tile read once per block (was twice with N-split).

__global__ __launch_bounds__(256) void gemm_mfma(const __half* __restrict__ H,
                                                 const ushort* __restrict__ Wt2,
                                                 const float* __restrict__ bias2,
                                                 __half* __restrict__ out, int M) {
    __shared__ __attribute__((aligned(16))) ushort Ah[128][40];
    __shared__ __attribute__((aligned(16))) ushort Bh[256][40];
    int tid = threadIdx.x;
    int wid = tid >> 6, lane = tid & 63;
    int m0 = blockIdx.x * 128;
    const ushort* Hu = (const ushort*)H;

    f32x4 acc[2][16];
#pragma unroll
    for (int m = 0; m < 2; m++)
#pragma unroll
        for (int n = 0; n < 16; n++) acc[m][n] = (f32x4){0.f, 0.f, 0.f, 0.f};

    int sr2 = tid >> 2;              // 0..63
    int kq2 = (tid & 3) << 3;        // 0,8,16,24
    int fr = lane & 15;
    int qo = (lane >> 4) << 3;
    int mrow = wid << 5;

    for (int k0 = 0; k0 < 256; k0 += 32) {
#pragma unroll
        for (int t = 0; t < 2; t++) {
            int r = sr2 + t * 64;
            int gr = m0 + r; if (gr >= M) gr = M - 1;
            *(uint4*)&Ah[r][kq2] = *(const uint4*)(Hu + gr * 256 + k0 + kq2);
        }
#pragma unroll
        for (int t = 0; t < 4; t++) {
            int r = sr2 + t * 64;
            *(uint4*)&Bh[r][kq2] = *(const uint4*)(Wt2 + r * 256 + k0 + kq2);
        }
        __syncthreads();

        f16x8 a0 = *(const f16x8*)&Ah[mrow + fr][qo];
        f16x8 a1 = *(const f16x8*)&Ah[mrow + 16 + fr][qo];
#pragma unroll
        for (int nt = 0; nt < 16; nt++) {
            f16x8 bb = *(const f16x8*)&Bh[nt * 16 + fr][qo];
            acc[0][nt] = __builtin_amdgcn_mfma_f32_16x16x32_f16(a0, bb, acc[0][nt], 0, 0, 0);
            acc[1][nt] = __builtin_amdgcn_mfma_f32_16x16x32_f16(a1, bb, acc[1][nt], 0, 0, 0);
        }
        __syncthreads();
    }

#pragma unroll
    for (int mt = 0; mt < 2; mt++) {
        int gmb = m0 + mrow + mt * 16 + ((lane >> 4) << 2);
#pragma unroll
        for (int nt = 0; nt < 16; nt++) {
            int gn = nt * 16 + fr;
            float bv = bias2[gn];
#pragma unroll
            for (int j = 0; j < 4; j++) {
                int gm = gmb + j;
                if (gm < M) out[gm * 256 + gn] = __float2half(acc[mt][nt][j] + bv);
            }
        }
    }
}

// ---------------- SpMM fp16: 2 edges/wave, 16B loads, fused column stats ----------------

__global__ __launch_bounds__(256) void spmm_f16w(const __half* __restrict__ T,
                                                 const int2* __restrict__ se,
                                                 const int* __restrict__ off,
                                                 __half* __restrict__ outp,
                                                 float* __restrict__ sp, int N) {
    __shared__ float red[4][512];
    int tid = threadIdx.x;
    int wid = tid >> 6, lane = tid & 63;
    int hh = lane >> 5;
    int li = lane & 31;
    int colb = li << 3;
    const ushort* Tu = (const ushort*)T;
    ushort* Ou = (ushort*)outp;
    float cs[8] = {0, 0, 0, 0, 0, 0, 0, 0}, cq[8] = {0, 0, 0, 0, 0, 0, 0, 0};
    int gw = blockIdx.x * 4 + wid, nw = gridDim.x * 4;
    for (int n = gw; n < N; n += nw) {
        int e0 = off[n], e1 = off[n + 1];
        float acc[8] = {0, 0, 0, 0, 0, 0, 0, 0};
        int e = e0;
        for (; e + 7 < e1; e += 8) {
            int2 s[4]; US8 v[4];
#pragma unroll
            for (int i = 0; i < 4; i++) s[i] = se[e + 2 * i + hh];
#pragma unroll
            for (int i = 0; i < 4; i++) v[i].u = *(const uint4*)(Tu + s[i].x * 256 + colb);
#pragma unroll
            for (int i = 0; i < 4; i++) {
                float w = __int_as_float(s[i].y);
#pragma unroll
                for (int j = 0; j < 8; j++) acc[j] += w * __half2float(v[i].h[j]);
            }
        }
        for (; e < e1; e += 2) {
            if (e + hh < e1) {
                int2 s = se[e + hh];
                float w = __int_as_float(s.y);
                US8 v; v.u = *(const uint4*)(Tu + s.x * 256 + colb);
#pragma unroll
                for (int j = 0; j < 8; j++) acc[j] += w * __half2float(v.h[j]);
            }
        }
        US8 o;
#pragma unroll
        for (int j = 0; j < 8; j++) {
            float other = __shfl(acc[j], lane ^ 32, 64);
            float s = fmaxf(acc[j] + other, 0.f);
            o.h[j] = __float2half(s);
            if (hh == 0) { cs[j] += s; cq[j] += s * s; }
        }
        if (hh == 0) *(uint4*)(Ou + n * 256 + colb) = o.u;
    }
    if (hh == 0) {
#pragma unroll
        for (int j = 0; j < 8; j++) {
            red[wid][colb + j] = cs[j];
            red[wid][256 + colb + j] = cq[j];
        }
    }
    __syncthreads();
    float* dst = sp + (blockIdx.x & 15) * 512;
    for (int i = tid; i < 512; i += 256)
        atomicAdd(&dst[i], red[0][i] + red[1][i] + red[2][i] + red[3][i]);
}

__global__ __launch_bounds__(256) void spmm_small(const float* __restrict__ T,
                                                  const int2* __restrict__ se,
                                                  const int* __restrict__ off,
                                                  float* __restrict__ out,
                                                  int C, int N, int relu) {
    int npb = blockDim.x / C;
    int local = threadIdx.x / C;
    int c = threadIdx.x % C;
    int n = blockIdx.x * npb + local;
    if (n >= N) return;
    int e0 = off[n], e1 = off[n + 1];
    float acc = 0.f;
    for (int e = e0; e < e1; ++e) {
        int2 s = se[e];
        acc += __int_as_float(s.y) * T[s.x * C + c];
    }
    if (relu) acc = fmaxf(acc, 0.f);
    out[n * C + c] = acc;
}

// ---------------- layer 0 finalize + fused column stats ----------------

__global__ __launch_bounds__(256) void layer0_fin(const float* __restrict__ agg2,
                                                  const float* __restrict__ w_in,
                                                  const float* __restrict__ st,
                                                  const float* __restrict__ W0,
                                                  const float* __restrict__ b0,
                                                  __half* __restrict__ h,
                                                  float* __restrict__ sp, int N) {
    int j = threadIdx.x;
    float w0j = W0[j], w1j = W0[256 + j], b0j = b0[j];
    float s0 = st[0], s1 = st[1], t0 = st[2], t1 = st[3];
    float cs = 0.f, cq = 0.f;
    for (int n = blockIdx.x; n < N; n += gridDim.x) {
        float wi = w_in[n];
        float a0 = agg2[n * 2 + 0] * s0 + wi * t0;
        float a1 = agg2[n * 2 + 1] * s1 + wi * t1;
        float v = fmaxf(a0 * w0j + a1 * w1j + wi * b0j, 0.f);
        h[n * 256 + j] = __float2half(v);
        cs += v; cq += v * v;
    }
    float* dst = sp + (blockIdx.x & 15) * 512;
    atomicAdd(&dst[j], cs);
    atomicAdd(&dst[256 + j], cq);
}

// ---------------- last GCN linear: [M,256]f16 x [256,16] ----------------

__global__ __launch_bounds__(256) void gemm16(const __half* __restrict__ H,
                                              const float* __restrict__ Wl,
                                              const float* __restrict__ bl,
                                              const float* __restrict__ st,
                                              float* __restrict__ out, int M) {
    __shared__ float Hs[16][256];
    __shared__ float Ws[256][16];
    int tid = threadIdx.x;
    int n0 = blockIdx.x << 4;
    const ushort* Hu = (const ushort*)H;
    for (int i = tid; i < 4096; i += 256) Ws[i >> 4][i & 15] = Wl[i];
    for (int i = tid; i < 4096; i += 256) {
        int r = i >> 8, k = i & 255;
        int n = n0 + r;
        float hv = 0.f;
        if (n < M) hv = h2f(Hu[n * 256 + k]) * st[k] + st[256 + k];
        Hs[r][k] = hv;
    }
    __syncthreads();
    int r = tid >> 4, j = tid & 15;
    float acc = bl[j];
    for (int k = 0; k < 256; k++) acc += Hs[r][k] * Ws[k][j];
    if (n0 + r < M) out[(n0 + r) * 16 + j] = acc;
}

// ---------------- z prep: z = fp16(bn(hraw)) ----------------

__global__ void zprep(const float* __restrict__ hraw, const float* __restrict__ st,
                      ushort* __restrict__ Z, int NE) {
    int i = blockIdx.x * blockDim.x + threadIdx.x;
    if (i >= NE) return;
    int c = i & 15;
    Z[i] = f2h(hraw[i] * st[c] + st[16 + c]);
}

// ---------------- unweighted 16-wide spmm ----------------

__global__ __launch_bounds__(256) void aggz_spmm(const ushort* __restrict__ Z,
                                                 const int2* __restrict__ se,
                                                 const int* __restrict__ off,
                                                 float* __restrict__ aggz, int N) {
    int local = threadIdx.x >> 4;
    int c = threadIdx.x & 15;
    int n = blockIdx.x * 16 + local;
    if (n >= N) return;
    int e0 = off[n], e1 = off[n + 1];
    float acc = 0.f;
    for (int e = e0; e < e1; ++e) acc += h2f(Z[se[e].x * 16 + c]);
    aggz[n * 16 + c] = acc;
}

// ---------------- node moments: P, R, M, Sdout, Sdin ----------------

__global__ __launch_bounds__(256) void zmom(const ushort* __restrict__ Z,
                                            const float* __restrict__ aggz,
                                            const int* __restrict__ dout,
                                            const unsigned long long* __restrict__ cw,
                                            float* __restrict__ MOM, int N) {
    __shared__ float zs[128][17];
    __shared__ float az[128][17];
    __shared__ float dw[128][2];
    int tid = threadIdx.x;
    int i = tid >> 4, j = tid & 15;
    float p = 0.f, r = 0.f, m = 0.f, sdo = 0.f, sdi = 0.f;
    for (int base = blockIdx.x * 128; base < N; base += gridDim.x * 128) {
        int cnt = N - base; if (cnt > 128) cnt = 128;
        for (int t = tid; t < 2048; t += 256) {
            int n = t >> 4, c = t & 15;
            if (n < cnt) {
                zs[n][c] = h2f(Z[(base + n) * 16 + c]);
                az[n][c] = aggz[(base + n) * 16 + c];
            } else { zs[n][c] = 0.f; az[n][c] = 0.f; }
        }
        for (int t = tid; t < 128; t += 256) {
            if (t < cnt) {
                dw[t][0] = (float)dout[base + t];
                dw[t][1] = (float)(int)(cw[base + t] >> 40);
            } else { dw[t][0] = 0.f; dw[t][1] = 0.f; }
        }
        __syncthreads();
        for (int n = 0; n < 128; n++) {
            float zi = zs[n][i], zj = zs[n][j];
            float d0 = dw[n][0], d1 = dw[n][1];
            float zz = zi * zj;
            p += d0 * zz;
            r += d1 * zz;
            m += az[n][i] * zj;
            if (i == 0) { sdo += d0 * zj; sdi += d1 * zj; }
        }
        __syncthreads();
    }
    float* dst = MOM + (blockIdx.x & 15) * 800;
    atomicAdd(&dst[tid], p);
    atomicAdd(&dst[256 + tid], r);
    atomicAdd(&dst[512 + tid], m);
    if (i == 0) { atomicAdd(&dst[768 + j], sdo); atomicAdd(&dst[784 + j], sdi); }
}

// ---------------- analytic edge-MLP BN affine + prescaled W' + linear-term vector ----------------
// abw: [0..511] bias' | [512..1023] w | [1024..1055] g32 | [1056] cbeta

__global__ __launch_bounds__(256) void mlp_ab(const float* __restrict__ MOM,
                                              const float* __restrict__ mW1,
                                              const float* __restrict__ g,
                                              const float* __restrict__ b,
                                              const float* __restrict__ mW2,
                                              float* __restrict__ abw,
                                              ushort* __restrict__ Wp2, int E) {
    __shared__ float P[256], R[256], Mm[256], Sdo[16], Sdi[16];
    __shared__ float gsh[33];
    int tid = threadIdx.x;
    if (tid < 33) gsh[tid] = 0.f;
    float sp = 0.f, sr = 0.f, sm = 0.f;
#pragma unroll
    for (int q = 0; q < 16; q++) {
        sp += MOM[q * 800 + tid];
        sr += MOM[q * 800 + 256 + tid];
        sm += MOM[q * 800 + 512 + tid];
    }
    P[tid] = sp; R[tid] = sr; Mm[tid] = sm;
    if (tid < 16) {
        float a = 0.f, c = 0.f;
#pragma unroll
        for (int q = 0; q < 16; q++) { a += MOM[q * 800 + 768 + tid]; c += MOM[q * 800 + 784 + tid]; }
        Sdo[tid] = a; Sdi[tid] = c;
    }
    __syncthreads();
    int j = tid;
    float A[16], B[16];
#pragma unroll
    for (int k = 0; k < 16; k++) { A[k] = mW1[k * 256 + j]; B[k] = mW1[(16 + k) * 256 + j]; }
    float apa = 0.f, brb = 0.f, amb = 0.f, bpb = 0.f, ara = 0.f, bma = 0.f;
    float aso = 0.f, bso = 0.f, asi = 0.f, bsi = 0.f;
    for (int i2 = 0; i2 < 16; i2++) {
        float Ai = A[i2], Bi = B[i2];
        aso += Ai * Sdo[i2]; bso += Bi * Sdo[i2];
        asi += Ai * Sdi[i2]; bsi += Bi * Sdi[i2];
#pragma unroll
        for (int k = 0; k < 16; k++) {
            float Pik = P[i2 * 16 + k], Rik = R[i2 * 16 + k], Mik = Mm[i2 * 16 + k];
            apa += Ai * Pik * A[k]; brb += Bi * Rik * B[k]; amb += Ai * Mik * B[k];
            bpb += Bi * Pik * B[k]; ara += Ai * Rik * A[k]; bma += Bi * Mik * A[k];
        }
    }
    float invE = 1.f / (float)E;
    float mu1 = (aso + bsi) * invE;
    float mu2 = (bso + asi) * invE;
    float e21 = (apa + brb + 2.f * amb) * invE;
    float e22 = (bpb + ara + 2.f * bma) * invE;
    float a1 = g[j] * rsqrtf(e21 - mu1 * mu1 + 1e-5f);
    float a2 = g[j] * rsqrtf(e22 - mu2 * mu2 + 1e-5f);
    float b1p = b[j] - mu1 * a1;
    float b2p = b[j] - mu2 * a2;
    float w = mW2[j];
    abw[j] = b1p; abw[256 + j] = b2p;
    abw[512 + j] = w; abw[768 + j] = w;
#pragma unroll
    for (int k = 0; k < 16; k++) {
        Wp2[j * 32 + k]              = f2h(a1 * A[k]);
        Wp2[j * 32 + 16 + k]         = f2h(a1 * B[k]);
        Wp2[(256 + j) * 32 + k]      = f2h(a2 * B[k]);
        Wp2[(256 + j) * 32 + 16 + k] = f2h(a2 * A[k]);
    }
#pragma unroll
    for (int k = 0; k < 16; k++) {
        atomicAdd(&gsh[k],      w * (a1 * A[k] + a2 * B[k]));
        atomicAdd(&gsh[16 + k], w * (a1 * B[k] + a2 * A[k]));
    }
    atomicAdd(&gsh[32], w * (b1p + b2p));
    __syncthreads();
    if (tid < 32) abw[1024 + tid] = gsh[tid];
    if (tid == 0) abw[1056] = gsh[32];
}

// ---------------- per-node linear term ----------------

__global__ __launch_bounds__(256) void gprep(const ushort* __restrict__ Z,
                                             const float* __restrict__ abw,
                                             float2* __restrict__ G, int N) {
    __shared__ float gs[32];
    if (threadIdx.x < 32) gs[threadIdx.x] = abw[1024 + threadIdx.x];
    __syncthreads();
    int n = blockIdx.x * blockDim.x + threadIdx.x;
    if (n >= N) return;
    float g1 = 0.f, g2 = 0.f;
#pragma unroll
    for (int k = 0; k < 16; k++) {
        float z = h2f(Z[n * 16 + k]);
        g1 += z * gs[k];
        g2 += z * gs[16 + k];
    }
    G[n] = make_float2(g1, g2);
}

// ---------------- edge MLP output: MFMA (bias in C-operand) + abs-trick ----------------
// w*relu(s) = 0.5*(w*s + w*|s|); linear part in lin[]; bias added by matrix unit
// (C_in = {bv,bv,bv,bv}); epilogue = 1 fma-with-abs per value.
// #pragma unroll 1 caps the live-register window (rounds 7/8: full unroll -> spill).

__global__ __launch_bounds__(256) void edge_mfma(const ushort* __restrict__ Z,
                                                 const int* __restrict__ ei,
                                                 const ushort* __restrict__ Wp2,
                                                 const float* __restrict__ abw,
                                                 const float2* __restrict__ G,
                                                 const float* __restrict__ mb2,
                                                 float* __restrict__ out, int E) {
    __shared__ __attribute__((aligned(16))) ushort As[256][32];
    __shared__ __attribute__((aligned(16))) ushort Bs[512][32];
    __shared__ float lin[256];
    int tid = threadIdx.x;
    int wid = tid >> 6, lane = tid & 63;
    int fr = lane & 15, qo = (lane >> 4) << 3;

    // stage W' (prescaled) into LDS
    for (int i = tid * 4; i < 512 * 32; i += 1024) {
        int n = i >> 5, k = i & 31;
        *(ushort4*)&Bs[n][k] = *(const ushort4*)(Wp2 + i);
    }
    float cb = abw[1056];
    int e0 = blockIdx.x * 256;
    {
        int e = e0 + tid;
        int r = 0, c = 0;
        if (e < E) { r = ei[e]; c = ei[E + e]; }
        uint4 z0 = *(const uint4*)(Z + r * 16);
        uint4 z1 = *(const uint4*)(Z + r * 16 + 8);
        uint4 z2 = *(const uint4*)(Z + c * 16);
        uint4 z3 = *(const uint4*)(Z + c * 16 + 8);
        *(uint4*)&As[tid][0]  = z0; *(uint4*)&As[tid][8]  = z1;
        *(uint4*)&As[tid][16] = z2; *(uint4*)&As[tid][24] = z3;
        float2 gr = G[r], gc = G[c];
        lin[tid] = gr.x + gc.y + cb;
    }
    __syncthreads();

    f16x8 a[4];
#pragma unroll
    for (int mt = 0; mt < 4; mt++) a[mt] = *(const f16x8*)&As[(wid * 4 + mt) * 16 + fr][qo];
    float pacc[4][4];
#pragma unroll
    for (int mt = 0; mt < 4; mt++)
#pragma unroll
        for (int j = 0; j < 4; j++) pacc[mt][j] = 0.f;
    float mb2v = mb2[0];

#pragma unroll 1
    for (int n = 0; n < 32; n++) {
        f16x8 bfr = *(const f16x8*)&Bs[n * 16 + fr][qo];
        int col = n * 16 + fr;
        float bv = abw[col], wv = abw[512 + col];
        f32x4 cin = {bv, bv, bv, bv};
#pragma unroll
        for (int mt = 0; mt < 4; mt++) {
            f32x4 c0 = __builtin_amdgcn_mfma_f32_16x16x32_f16(a[mt], bfr, cin, 0, 0, 0);
#pragma unroll
            for (int j = 0; j < 4; j++)
                pacc[mt][j] = fmaf(wv, fabsf(c0[j]), pacc[mt][j]);
        }
    }

#pragma unroll
    for (int mt = 0; mt < 4; mt++)
#pragma unroll
        for (int j = 0; j < 4; j++) {
            float p = pacc[mt][j];
            p += __shfl_xor(p, 1);
            p += __shfl_xor(p, 2);
            p += __shfl_xor(p, 4);
            p += __shfl_xor(p, 8);
            if (fr == 0) {
                int row = (wid * 4 + mt) * 16 + ((lane >> 4) << 2) + j;
                int e = e0 + row;
                if (e < E) out[e] = 1.f / (1.f + expf(-(0.25f * (lin[row] + p) + mb2v)));
            }
        }
}

// ---------------- launch ----------------

extern "C" void kernel_launch(void* const* d_in, const int* in_sizes, int n_in,
                              void* d_out, int out_size, void* d_ws, size_t ws_size,
                              hipStream_t stream) {
    const float* x     = (const float*)d_in[0];
    const int*   ei    = (const int*)d_in[1];
    const float* ew    = (const float*)d_in[2];
    const float* W0    = (const float*)d_in[3];
    const float* b0    = (const float*)d_in[4];
    const float* Wm    = (const float*)d_in[5];
    const float* bm    = (const float*)d_in[6];
    const float* Wl    = (const float*)d_in[7];
    const float* bl    = (const float*)d_in[8];
    const float* bn0_g = (const float*)d_in[9];
    const float* bn0_b = (const float*)d_in[10];
    const float* bnm_g = (const float*)d_in[11];
    const float* bnm_b = (const float*)d_in[12];
    const float* bno_g = (const float*)d_in[13];
    const float* bno_b = (const float*)d_in[14];
    const float* mW1   = (const float*)d_in[15];
    const float* mbn_g = (const float*)d_in[17];
    const float* mbn_b = (const float*)d_in[18];
    const float* mW2   = (const float*)d_in[19];
    const float* mb2   = (const float*)d_in[20];
    float* outp = (float*)d_out;

    char* ws = (char*)d_ws;
    unsigned long long* cw = (unsigned long long*)(ws + OFF_CW);
    int*    dout    = (int*)(ws + OFF_DOUT);
    float*  stats2  = (float*)(ws + OFF_STATS2);
    float*  sp8     = (float*)(ws + OFF_SP8);
    float*  MOM     = (float*)(ws + OFF_MOM);
    float*  st      = (float*)(ws + OFF_ST);
    float*  abw     = (float*)(ws + OFF_ABW);
    float*  w_in    = (float*)(ws + OFF_WIN);
    int*    offsets = (int*)(ws + OFF_OFFSETS);
    int2*   se      = (int2*)(ws + OFF_SE);
    int*    rank    = (int*)(ws + OFF_RANK);
    ushort* Wt      = (ushort*)(ws + OFF_WT);
    __half* bufQ    = (__half*)(ws + OFF_BUFQ);
    __half* bufP    = (__half*)(ws + OFF_BUFP);
    ushort* Wt2     = (ushort*)(ws + OFF_RANK + ALI_WT2);
    float*  bias2   = (float*)(ws + OFF_RANK + ALI_BIAS2);
    float2* G       = (float2*)(ws + OFF_RANK + ALI_G);
    float*  agg2    = (float*)(ws + OFF_BUFQ + ALI_TMP16);
    float*  tmp16   = (float*)(ws + OFF_BUFQ + ALI_TMP16);
    float*  hraw    = (float*)(ws + OFF_BUFQ + ALI_HRAW);
    ushort* Z       = (ushort*)(ws + OFF_BUFQ + ALI_Z);
    float*  aggz    = (float*)(ws + OFF_BUFQ + ALI_AGGZ);
    ushort* Wp2     = (ushort*)(ws + OFF_RANK + ALI_WT2);  // reuse Wt2 slot (dead by then)

    const int N = NNODES, E = NEDGES;

    hipMemsetAsync(ws, 0, ZERO_END, stream);

    // CSR build (rank-based) + weight preconvert
    hist_kernel<<<1024, 256, 0, stream>>>(ei, ew, cw, dout, rank, E);
    wconv<<<640, 256, 0, stream>>>(Wm, Wt);
    scan_kernel<<<1, 1024, 0, stream>>>(cw, offsets, w_in, N);
    scatter_kernel<<<1024, 256, 0, stream>>>(ei, ew, offsets, rank, se, E);

    // ---- layer 0 ----
    colstats_wr<<<64, 256, 0, stream>>>(x, stats2 + 0 * 512, 2, N);
    bn_finalize<<<1, 256, 0, stream>>>(stats2 + 0 * 512, bn0_g, bn0_b, st, 2, N);
    spmm_small<<<(N + 127) / 128, 256, 0, stream>>>(x, se, offsets, agg2, 2, N, 0);
    layer0_fin<<<512, 256, 0, stream>>>(agg2, w_in, st, W0, b0, bufP, sp8 + 0 * 8192, N);

    // ---- 10 mid layers ----
    for (int i = 0; i < 10; i++) {
        bnw<<<64, 256, 0, stream>>>(sp8 + i * 8192, bnm_g + i * 256, bnm_b + i * 256,
                                    Wt + i * 65536, bm + i * 256, Wt2, bias2, N);
        gemm_mfma<<<(N + 127) / 128, 256, 0, stream>>>(bufP, Wt2, bias2, bufQ, N);
        spmm_f16w<<<2048, 256, 0, stream>>>(bufQ, se, offsets, bufP,
                                            sp8 + (i + 1) * 8192, N);
    }

    // ---- last GCN layer (256 -> 16) ----
    bn_finalize16<<<1, 256, 0, stream>>>(sp8 + 10 * 8192, bnm_g + 10 * 256,
                                         bnm_b + 10 * 256, st, N);
    gemm16<<<(N + 15) / 16, 256, 0, stream>>>(bufP, Wl, bl, st, tmp16, N);
    spmm_small<<<(N + 15) / 16, 256, 0, stream>>>(tmp16, se, offsets, hraw, 16, N, 1);

    // ---- final BN -> z (fp16) ----
    colstats_wr<<<64, 256, 0, stream>>>(hraw, stats2 + 1 * 512, 16, N);
    bn_finalize<<<1, 256, 0, stream>>>(stats2 + 1 * 512, bno_g, bno_b, st, 16, N);
    zprep<<<(N * 16 + 255) / 256, 256, 0, stream>>>(hraw, st, Z, N * 16);

    // ---- analytic edge-MLP BN stats + prescaled weights ----
    aggz_spmm<<<(N + 15) / 16, 256, 0, stream>>>(Z, se, offsets, aggz, N);
    zmom<<<256, 256, 0, stream>>>(Z, aggz, dout, cw, MOM, N);
    mlp_ab<<<1, 256, 0, stream>>>(MOM, mW1, mbn_g, mbn_b, mW2, abw, Wp2, E);
    gprep<<<(N + 255) / 256, 256, 0, stream>>>(Z, abw, G, N);

    // ---- edge MLP output (MFMA, bias-in-C, abs-trick) ----
    edge_mfma<<<(E + 255) / 256, 256, 0, stream>>>(Z, ei, Wp2, abw, G, mb2, outp, E);
}

// Round 11
// 1478.264 us; speedup vs baseline: 1.0967x; 1.0967x over previous
//
#include <hip/hip_runtime.h>
#include <hip/hip_bf16.h>
#include <hip/hip_fp16.h>
#include <math.h>

#define NNODES 50000
#define NEDGES 800000

// ---------------- workspace layout (bytes) ----------------
#define OFF_CW       0ull                      // u64[50000] packed count|w_in (zeroed)
#define OFF_DOUT     401408ull                 // int[50000] (zeroed)
#define OFF_STATS2   602112ull                 // float[2*512] (zeroed)
#define OFF_SP8      606208ull                 // float[11*16*512] (zeroed)
#define OFF_MOM      966656ull                 // float[16*800] (zeroed)
#define ZERO_END     1017856ull
#define OFF_ST       1017856ull                // float[512]
#define OFF_ABW      1019904ull                // float[1536]: bb[512]|ww[512]|g32[32]|cb
#define OFF_WIN      1026048ull                // float[50000]
#define OFF_OFFSETS  1226752ull                // int[50001]
#define OFF_SE       1427456ull                // int2[800000] packed (srow, ew)
#define OFF_RANK     7827456ull                // int[800000]; aliased after scatter:
#define ALI_WT2      0ull                      //   ushort[256*256] (later Wp2)
#define ALI_BIAS2    131072ull                 //   float[256]
#define ALI_G        132096ull                 //   float2[50000]
#define OFF_WT       11027456ull               // ushort[10*256*256] fp16 W (transposed)
#define OFF_BUFQ     12371968ull               // half[50000*256]
#define OFF_BUFP     37971968ull               // half[50000*256]
// aliases inside dead BUFQ (after 10th spmm; agg2 dead before 1st gemm):
#define ALI_TMP16    0ull                      // float[50000*16]
#define ALI_HRAW     3276800ull                // float[50000*16]
#define ALI_Z        6553600ull                // ushort[50000*16]
#define ALI_AGGZ     8388608ull                // float[50000*16]

typedef __attribute__((ext_vector_type(8))) _Float16 f16x8;
typedef __attribute__((ext_vector_type(4))) float f32x4;

union H4 { ushort4 u; __half h[4]; };
union US8 { uint4 u; __half h[8]; };
union HU { ushort u; __half h; };

static __device__ inline ushort f2h(float f) {
    HU cv; cv.h = __float2half(f); return cv.u;
}
static __device__ inline float h2f(ushort u) {
    HU cv; cv.u = u; return __half2float(cv.h);
}

// ---------------- preprocessing ----------------

__global__ void hist_kernel(const int* __restrict__ ei, const float* __restrict__ ew,
                            unsigned long long* __restrict__ cw, int* __restrict__ dout,
                            int* __restrict__ rank, int E) {
    for (int i = blockIdx.x * blockDim.x + threadIdx.x; i < E; i += gridDim.x * blockDim.x) {
        int r = ei[i];
        int c = ei[E + i];
        unsigned long long pack = (1ull << 40) |
            (unsigned long long)__float2uint_rn(ew[i] * 1048576.f);
        unsigned long long old = atomicAdd(&cw[c], pack);
        rank[i] = (int)(old >> 40);
        atomicAdd(&dout[r], 1);
    }
}

__global__ void scan_kernel(const unsigned long long* __restrict__ cw,
                            int* __restrict__ offsets, float* __restrict__ w_in, int N) {
    __shared__ int wsum[16];
    __shared__ int carry_s;
    int tid = threadIdx.x;
    int lane = tid & 63, w = tid >> 6;
    if (tid == 0) carry_s = 0;
    __syncthreads();
    for (int base = 0; base < N; base += 1024) {
        int v = 0;
        if (base + tid < N) {
            unsigned long long cv = cw[base + tid];
            v = (int)(cv >> 40);
            w_in[base + tid] = (float)(cv & 0xFFFFFFFFFFull) * (1.f / 1048576.f);
        }
        int x = v;
#pragma unroll
        for (int off = 1; off < 64; off <<= 1) {
            int y = __shfl_up(x, off);
            if (lane >= off) x += y;
        }
        if (lane == 63) wsum[w] = x;
        __syncthreads();
        if (w == 0 && lane < 16) {
            int s = wsum[lane];
#pragma unroll
            for (int off = 1; off < 16; off <<= 1) {
                int y = __shfl_up(s, off);
                if (lane >= off) s += y;
            }
            wsum[lane] = s;
        }
        __syncthreads();
        int wbase = (w > 0) ? wsum[w - 1] : 0;
        int incl = carry_s + wbase + x;
        if (base + tid < N) offsets[base + tid] = incl - v;
        __syncthreads();
        if (tid == 0) carry_s += wsum[15];
        __syncthreads();
    }
    if (tid == 0) offsets[N] = carry_s;
}

__global__ void scatter_kernel(const int* __restrict__ ei, const float* __restrict__ ew,
                               const int* __restrict__ offsets, const int* __restrict__ rank,
                               int2* __restrict__ se, int E) {
    for (int i = blockIdx.x * blockDim.x + threadIdx.x; i < E; i += gridDim.x * blockDim.x) {
        int c = ei[E + i];
        int p = offsets[c] + rank[i];
        se[p] = make_int2(ei[i], __float_as_int(ew[i]));
    }
}

// ---------------- weight preconvert: Wt[n][k] = fp16(Wm[k][n]) ----------------

__global__ __launch_bounds__(256) void wconv(const float* __restrict__ Wm,
                                             ushort* __restrict__ Wt) {
    __shared__ float tile[32][33];
    int b = blockIdx.x;
    int layer = b >> 6, t = b & 63;
    int tk = (t >> 3) << 5, tn = (t & 7) << 5;
    int tid = threadIdx.x;
    int r = tid >> 5, c = tid & 31;
    const float* W = Wm + layer * 65536;
#pragma unroll
    for (int i = 0; i < 4; i++) tile[r + i * 8][c] = W[(tk + r + i * 8) * 256 + tn + c];
    __syncthreads();
#pragma unroll
    for (int i = 0; i < 4; i++) {
        int n = tn + r + i * 8, k = tk + c;
        Wt[layer * 65536 + n * 256 + k] = f2h(tile[c][r + i * 8]);
    }
}

// ---------------- small-C column stats (wave-reduced) ----------------

__global__ __launch_bounds__(256) void colstats_wr(const float* __restrict__ h,
                                                   float* __restrict__ sums, int C, int M) {
    int gtid = blockIdx.x * blockDim.x + threadIdx.x;
    int lane = threadIdx.x & 63;
    int c = gtid % C;
    int r = gtid / C;
    int stride = (gridDim.x * blockDim.x) / C;
    float s = 0.f, q = 0.f;
    for (; r < M; r += stride) {
        float v = h[r * C + c];
        s += v; q += v * v;
    }
    for (int m = 32; m >= C; m >>= 1) {
        s += __shfl_xor(s, m);
        q += __shfl_xor(q, m);
    }
    if (lane < C) {
        atomicAdd(&sums[c], s);
        atomicAdd(&sums[C + c], q);
    }
}

__global__ void bn_finalize(const float* __restrict__ sums, const float* __restrict__ g,
                            const float* __restrict__ b, float* __restrict__ st, int C, int M) {
    int c = threadIdx.x;
    if (c >= C) return;
    float mean = sums[c] / (float)M;
    float var  = sums[C + c] / (float)M - mean * mean;
    float sc = g[c] * rsqrtf(var + 1e-5f);
    st[c] = sc;
    st[C + c] = b[c] - mean * sc;
}

__global__ void bn_finalize16(const float* __restrict__ sp, const float* __restrict__ g,
                              const float* __restrict__ b, float* __restrict__ st, int M) {
    int c = threadIdx.x;
    float s = 0.f, q = 0.f;
#pragma unroll
    for (int p = 0; p < 16; p++) { s += sp[p * 512 + c]; q += sp[p * 512 + 256 + c]; }
    float mean = s / (float)M;
    float var  = q / (float)M - mean * mean;
    float sc = g[c] * rsqrtf(var + 1e-5f);
    st[c] = sc;
    st[256 + c] = b[c] - mean * sc;
}

// ---------------- per-layer weight fold: Wt2 = s∘Wt (fp16), bias2 = bias + t@W ----------------

__global__ __launch_bounds__(256) void bnw(const float* __restrict__ sp,
                                           const float* __restrict__ g,
                                           const float* __restrict__ b,
                                           const ushort* __restrict__ Wt,
                                           const float* __restrict__ bias,
                                           ushort* __restrict__ Wt2,
                                           float* __restrict__ bias2, int M) {
    __shared__ float st_s[512];
    int tid = threadIdx.x;
    {
        float s = 0.f, q = 0.f;
#pragma unroll
        for (int p = 0; p < 16; p++) { s += sp[p * 512 + tid]; q += sp[p * 512 + 256 + tid]; }
        float invM = 1.f / (float)M;
        float mean = s * invM;
        float var  = q * invM - mean * mean;
        float sc = g[tid] * rsqrtf(var + 1e-5f);
        st_s[tid] = sc;
        st_s[256 + tid] = b[tid] - mean * sc;
    }
    __syncthreads();
    int n = blockIdx.x * 4 + (tid >> 6);
    int k4 = (tid & 63) << 2;
    ushort4 w4 = *(const ushort4*)(Wt + n * 256 + k4);
    float4 s4 = *(const float4*)(st_s + k4);
    float4 t4 = *(const float4*)(st_s + 256 + k4);
    float w0 = h2f(w4.x), w1 = h2f(w4.y), w2 = h2f(w4.z), w3 = h2f(w4.w);
    ushort4 o;
    o.x = f2h(w0 * s4.x); o.y = f2h(w1 * s4.y);
    o.z = f2h(w2 * s4.z); o.w = f2h(w3 * s4.w);
    *(ushort4*)(Wt2 + n * 256 + k4) = o;
    float part = w0 * t4.x + w1 * t4.y + w2 * t4.z + w3 * t4.w;
#pragma unroll
    for (int m = 1; m < 64; m <<= 1) part += __shfl_xor(part, m);
    if ((tid & 63) == 0) bias2[n] = bias[n] + part;
}

// ---------------- MFMA GEMM (fp16, pre-folded BN): out = H@Wt2 + bias2 ----------------
// round-9 structure: grid (ceil(M/128), 2), acc[2][8] — best measured (1496 total).
// (round-10 full-width acc[2][16] cost ~14 µs/layer: occupancy/tail regression)

__global__ __launch_bounds__(256) void gemm_mfma(const __half* __restrict__ H,
                                                 const ushort* __restrict__ Wt2,
                                                 const float* __restrict__ bias2,
                                                 __half* __restrict__ out, int M) {
    __shared__ __attribute__((aligned(16))) ushort Ah[128][40];
    __shared__ __attribute__((aligned(16))) ushort Bh[128][40];
    int tid = threadIdx.x;
    int wid = tid >> 6, lane = tid & 63;
    int m0 = blockIdx.x * 128;
    int n0 = blockIdx.y * 128;
    const ushort* Hu = (const ushort*)H;

    f32x4 acc[2][8];
#pragma unroll
    for (int m = 0; m < 2; m++)
#pragma unroll
        for (int n = 0; n < 8; n++) acc[m][n] = (f32x4){0.f, 0.f, 0.f, 0.f};

    int sr = tid >> 3;
    int kq = (tid & 7) << 2;
    int fr = lane & 15;
    int qo = (lane >> 4) << 3;
    int mrow = wid << 5;

    for (int k0 = 0; k0 < 256; k0 += 32) {
#pragma unroll
        for (int t = 0; t < 4; t++) {
            int r = sr + t * 32;
            int gr = m0 + r; if (gr >= M) gr = M - 1;
            *(ushort4*)&Ah[r][kq] = *(const ushort4*)(Hu + gr * 256 + k0 + kq);
            *(ushort4*)&Bh[r][kq] = *(const ushort4*)(Wt2 + (n0 + r) * 256 + k0 + kq);
        }
        __syncthreads();

        f16x8 a0 = *(const f16x8*)&Ah[mrow + fr][qo];
        f16x8 a1 = *(const f16x8*)&Ah[mrow + 16 + fr][qo];
#pragma unroll
        for (int nt = 0; nt < 8; nt++) {
            f16x8 bb = *(const f16x8*)&Bh[nt * 16 + fr][qo];
            acc[0][nt] = __builtin_amdgcn_mfma_f32_16x16x32_f16(a0, bb, acc[0][nt], 0, 0, 0);
            acc[1][nt] = __builtin_amdgcn_mfma_f32_16x16x32_f16(a1, bb, acc[1][nt], 0, 0, 0);
        }
        __syncthreads();
    }

#pragma unroll
    for (int mt = 0; mt < 2; mt++) {
        int gmb = m0 + mrow + mt * 16 + ((lane >> 4) << 2);
#pragma unroll
        for (int nt = 0; nt < 8; nt++) {
            int gn = n0 + nt * 16 + fr;
            float bv = bias2[gn];
#pragma unroll
            for (int j = 0; j < 4; j++) {
                int gm = gmb + j;
                if (gm < M) out[gm * 256 + gn] = __float2half(acc[mt][nt][j] + bv);
            }
        }
    }
}

// ---------------- SpMM fp16: 2 edges/wave, 16B loads, fused column stats ----------------

__global__ __launch_bounds__(256) void spmm_f16w(const __half* __restrict__ T,
                                                 const int2* __restrict__ se,
                                                 const int* __restrict__ off,
                                                 __half* __restrict__ outp,
                                                 float* __restrict__ sp, int N) {
    __shared__ float red[4][512];
    int tid = threadIdx.x;
    int wid = tid >> 6, lane = tid & 63;
    int hh = lane >> 5;
    int li = lane & 31;
    int colb = li << 3;
    const ushort* Tu = (const ushort*)T;
    ushort* Ou = (ushort*)outp;
    float cs[8] = {0, 0, 0, 0, 0, 0, 0, 0}, cq[8] = {0, 0, 0, 0, 0, 0, 0, 0};
    int gw = blockIdx.x * 4 + wid, nw = gridDim.x * 4;
    for (int n = gw; n < N; n += nw) {
        int e0 = off[n], e1 = off[n + 1];
        float acc[8] = {0, 0, 0, 0, 0, 0, 0, 0};
        int e = e0;
        for (; e + 7 < e1; e += 8) {
            int2 s[4]; US8 v[4];
#pragma unroll
            for (int i = 0; i < 4; i++) s[i] = se[e + 2 * i + hh];
#pragma unroll
            for (int i = 0; i < 4; i++) v[i].u = *(const uint4*)(Tu + s[i].x * 256 + colb);
#pragma unroll
            for (int i = 0; i < 4; i++) {
                float w = __int_as_float(s[i].y);
#pragma unroll
                for (int j = 0; j < 8; j++) acc[j] += w * __half2float(v[i].h[j]);
            }
        }
        for (; e < e1; e += 2) {
            if (e + hh < e1) {
                int2 s = se[e + hh];
                float w = __int_as_float(s.y);
                US8 v; v.u = *(const uint4*)(Tu + s.x * 256 + colb);
#pragma unroll
                for (int j = 0; j < 8; j++) acc[j] += w * __half2float(v.h[j]);
            }
        }
        US8 o;
#pragma unroll
        for (int j = 0; j < 8; j++) {
            float other = __shfl(acc[j], lane ^ 32, 64);
            float s = fmaxf(acc[j] + other, 0.f);
            o.h[j] = __float2half(s);
            if (hh == 0) { cs[j] += s; cq[j] += s * s; }
        }
        if (hh == 0) *(uint4*)(Ou + n * 256 + colb) = o.u;
    }
    if (hh == 0) {
#pragma unroll
        for (int j = 0; j < 8; j++) {
            red[wid][colb + j] = cs[j];
            red[wid][256 + colb + j] = cq[j];
        }
    }
    __syncthreads();
    float* dst = sp + (blockIdx.x & 15) * 512;
    for (int i = tid; i < 512; i += 256)
        atomicAdd(&dst[i], red[0][i] + red[1][i] + red[2][i] + red[3][i]);
}

__global__ __launch_bounds__(256) void spmm_small(const float* __restrict__ T,
                                                  const int2* __restrict__ se,
                                                  const int* __restrict__ off,
                                                  float* __restrict__ out,
                                                  int C, int N, int relu) {
    int npb = blockDim.x / C;
    int local = threadIdx.x / C;
    int c = threadIdx.x % C;
    int n = blockIdx.x * npb + local;
    if (n >= N) return;
    int e0 = off[n], e1 = off[n + 1];
    float acc = 0.f;
    for (int e = e0; e < e1; ++e) {
        int2 s = se[e];
        acc += __int_as_float(s.y) * T[s.x * C + c];
    }
    if (relu) acc = fmaxf(acc, 0.f);
    out[n * C + c] = acc;
}

// ---------------- layer 0 finalize + fused column stats ----------------

__global__ __launch_bounds__(256) void layer0_fin(const float* __restrict__ agg2,
                                                  const float* __restrict__ w_in,
                                                  const float* __restrict__ st,
                                                  const float* __restrict__ W0,
                                                  const float* __restrict__ b0,
                                                  __half* __restrict__ h,
                                                  float* __restrict__ sp, int N) {
    int j = threadIdx.x;
    float w0j = W0[j], w1j = W0[256 + j], b0j = b0[j];
    float s0 = st[0], s1 = st[1], t0 = st[2], t1 = st[3];
    float cs = 0.f, cq = 0.f;
    for (int n = blockIdx.x; n < N; n += gridDim.x) {
        float wi = w_in[n];
        float a0 = agg2[n * 2 + 0] * s0 + wi * t0;
        float a1 = agg2[n * 2 + 1] * s1 + wi * t1;
        float v = fmaxf(a0 * w0j + a1 * w1j + wi * b0j, 0.f);
        h[n * 256 + j] = __float2half(v);
        cs += v; cq += v * v;
    }
    float* dst = sp + (blockIdx.x & 15) * 512;
    atomicAdd(&dst[j], cs);
    atomicAdd(&dst[256 + j], cq);
}

// ---------------- last GCN linear: [M,256]f16 x [256,16] ----------------

__global__ __launch_bounds__(256) void gemm16(const __half* __restrict__ H,
                                              const float* __restrict__ Wl,
                                              const float* __restrict__ bl,
                                              const float* __restrict__ st,
                                              float* __restrict__ out, int M) {
    __shared__ float Hs[16][256];
    __shared__ float Ws[256][16];
    int tid = threadIdx.x;
    int n0 = blockIdx.x << 4;
    const ushort* Hu = (const ushort*)H;
    for (int i = tid; i < 4096; i += 256) Ws[i >> 4][i & 15] = Wl[i];
    for (int i = tid; i < 4096; i += 256) {
        int r = i >> 8, k = i & 255;
        int n = n0 + r;
        float hv = 0.f;
        if (n < M) hv = h2f(Hu[n * 256 + k]) * st[k] + st[256 + k];
        Hs[r][k] = hv;
    }
    __syncthreads();
    int r = tid >> 4, j = tid & 15;
    float acc = bl[j];
    for (int k = 0; k < 256; k++) acc += Hs[r][k] * Ws[k][j];
    if (n0 + r < M) out[(n0 + r) * 16 + j] = acc;
}

// ---------------- z prep: z = fp16(bn(hraw)) ----------------

__global__ void zprep(const float* __restrict__ hraw, const float* __restrict__ st,
                      ushort* __restrict__ Z, int NE) {
    int i = blockIdx.x * blockDim.x + threadIdx.x;
    if (i >= NE) return;
    int c = i & 15;
    Z[i] = f2h(hraw[i] * st[c] + st[16 + c]);
}

// ---------------- unweighted 16-wide spmm ----------------

__global__ __launch_bounds__(256) void aggz_spmm(const ushort* __restrict__ Z,
                                                 const int2* __restrict__ se,
                                                 const int* __restrict__ off,
                                                 float* __restrict__ aggz, int N) {
    int local = threadIdx.x >> 4;
    int c = threadIdx.x & 15;
    int n = blockIdx.x * 16 + local;
    if (n >= N) return;
    int e0 = off[n], e1 = off[n + 1];
    float acc = 0.f;
    for (int e = e0; e < e1; ++e) acc += h2f(Z[se[e].x * 16 + c]);
    aggz[n * 16 + c] = acc;
}

// ---------------- node moments: P, R, M, Sdout, Sdin ----------------

__global__ __launch_bounds__(256) void zmom(const ushort* __restrict__ Z,
                                            const float* __restrict__ aggz,
                                            const int* __restrict__ dout,
                                            const unsigned long long* __restrict__ cw,
                                            float* __restrict__ MOM, int N) {
    __shared__ float zs[128][17];
    __shared__ float az[128][17];
    __shared__ float dw[128][2];
    int tid = threadIdx.x;
    int i = tid >> 4, j = tid & 15;
    float p = 0.f, r = 0.f, m = 0.f, sdo = 0.f, sdi = 0.f;
    for (int base = blockIdx.x * 128; base < N; base += gridDim.x * 128) {
        int cnt = N - base; if (cnt > 128) cnt = 128;
        for (int t = tid; t < 2048; t += 256) {
            int n = t >> 4, c = t & 15;
            if (n < cnt) {
                zs[n][c] = h2f(Z[(base + n) * 16 + c]);
                az[n][c] = aggz[(base + n) * 16 + c];
            } else { zs[n][c] = 0.f; az[n][c] = 0.f; }
        }
        for (int t = tid; t < 128; t += 256) {
            if (t < cnt) {
                dw[t][0] = (float)dout[base + t];
                dw[t][1] = (float)(int)(cw[base + t] >> 40);
            } else { dw[t][0] = 0.f; dw[t][1] = 0.f; }
        }
        __syncthreads();
        for (int n = 0; n < 128; n++) {
            float zi = zs[n][i], zj = zs[n][j];
            float d0 = dw[n][0], d1 = dw[n][1];
            float zz = zi * zj;
            p += d0 * zz;
            r += d1 * zz;
            m += az[n][i] * zj;
            if (i == 0) { sdo += d0 * zj; sdi += d1 * zj; }
        }
        __syncthreads();
    }
    float* dst = MOM + (blockIdx.x & 15) * 800;
    atomicAdd(&dst[tid], p);
    atomicAdd(&dst[256 + tid], r);
    atomicAdd(&dst[512 + tid], m);
    if (i == 0) { atomicAdd(&dst[768 + j], sdo); atomicAdd(&dst[784 + j], sdi); }
}

// ---------------- analytic edge-MLP BN affine + prescaled W' + linear-term vector ----------------
// abw: [0..511] bias' | [512..1023] w | [1024..1055] g32 | [1056] cbeta

__global__ __launch_bounds__(256) void mlp_ab(const float* __restrict__ MOM,
                                              const float* __restrict__ mW1,
                                              const float* __restrict__ g,
                                              const float* __restrict__ b,
                                              const float* __restrict__ mW2,
                                              float* __restrict__ abw,
                                              ushort* __restrict__ Wp2, int E) {
    __shared__ float P[256], R[256], Mm[256], Sdo[16], Sdi[16];
    __shared__ float gsh[33];
    int tid = threadIdx.x;
    if (tid < 33) gsh[tid] = 0.f;
    float sp = 0.f, sr = 0.f, sm = 0.f;
#pragma unroll
    for (int q = 0; q < 16; q++) {
        sp += MOM[q * 800 + tid];
        sr += MOM[q * 800 + 256 + tid];
        sm += MOM[q * 800 + 512 + tid];
    }
    P[tid] = sp; R[tid] = sr; Mm[tid] = sm;
    if (tid < 16) {
        float a = 0.f, c = 0.f;
#pragma unroll
        for (int q = 0; q < 16; q++) { a += MOM[q * 800 + 768 + tid]; c += MOM[q * 800 + 784 + tid]; }
        Sdo[tid] = a; Sdi[tid] = c;
    }
    __syncthreads();
    int j = tid;
    float A[16], B[16];
#pragma unroll
    for (int k = 0; k < 16; k++) { A[k] = mW1[k * 256 + j]; B[k] = mW1[(16 + k) * 256 + j]; }
    float apa = 0.f, brb = 0.f, amb = 0.f, bpb = 0.f, ara = 0.f, bma = 0.f;
    float aso = 0.f, bso = 0.f, asi = 0.f, bsi = 0.f;
    for (int i2 = 0; i2 < 16; i2++) {
        float Ai = A[i2], Bi = B[i2];
        aso += Ai * Sdo[i2]; bso += Bi * Sdo[i2];
        asi += Ai * Sdi[i2]; bsi += Bi * Sdi[i2];
#pragma unroll
        for (int k = 0; k < 16; k++) {
            float Pik = P[i2 * 16 + k], Rik = R[i2 * 16 + k], Mik = Mm[i2 * 16 + k];
            apa += Ai * Pik * A[k]; brb += Bi * Rik * B[k]; amb += Ai * Mik * B[k];
            bpb += Bi * Pik * B[k]; ara += Ai * Rik * A[k]; bma += Bi * Mik * A[k];
        }
    }
    float invE = 1.f / (float)E;
    float mu1 = (aso + bsi) * invE;
    float mu2 = (bso + asi) * invE;
    float e21 = (apa + brb + 2.f * amb) * invE;
    float e22 = (bpb + ara + 2.f * bma) * invE;
    float a1 = g[j] * rsqrtf(e21 - mu1 * mu1 + 1e-5f);
    float a2 = g[j] * rsqrtf(e22 - mu2 * mu2 + 1e-5f);
    float b1p = b[j] - mu1 * a1;
    float b2p = b[j] - mu2 * a2;
    float w = mW2[j];
    abw[j] = b1p; abw[256 + j] = b2p;
    abw[512 + j] = w; abw[768 + j] = w;
#pragma unroll
    for (int k = 0; k < 16; k++) {
        Wp2[j * 32 + k]              = f2h(a1 * A[k]);
        Wp2[j * 32 + 16 + k]         = f2h(a1 * B[k]);
        Wp2[(256 + j) * 32 + k]      = f2h(a2 * B[k]);
        Wp2[(256 + j) * 32 + 16 + k] = f2h(a2 * A[k]);
    }
#pragma unroll
    for (int k = 0; k < 16; k++) {
        atomicAdd(&gsh[k],      w * (a1 * A[k] + a2 * B[k]));
        atomicAdd(&gsh[16 + k], w * (a1 * B[k] + a2 * A[k]));
    }
    atomicAdd(&gsh[32], w * (b1p + b2p));
    __syncthreads();
    if (tid < 32) abw[1024 + tid] = gsh[tid];
    if (tid == 0) abw[1056] = gsh[32];
}

// ---------------- per-node linear term ----------------

__global__ __launch_bounds__(256) void gprep(const ushort* __restrict__ Z,
                                             const float* __restrict__ abw,
                                             float2* __restrict__ G, int N) {
    __shared__ float gs[32];
    if (threadIdx.x < 32) gs[threadIdx.x] = abw[1024 + threadIdx.x];
    __syncthreads();
    int n = blockIdx.x * blockDim.x + threadIdx.x;
    if (n >= N) return;
    float g1 = 0.f, g2 = 0.f;
#pragma unroll
    for (int k = 0; k < 16; k++) {
        float z = h2f(Z[n * 16 + k]);
        g1 += z * gs[k];
        g2 += z * gs[16 + k];
    }
    G[n] = make_float2(g1, g2);
}

// ---------------- edge MLP output: MFMA (bias in C-operand) + abs-trick ----------------
// w*relu(s) = 0.5*(w*s + w*|s|); linear part in lin[]; bias added by matrix unit
// (C_in = {bv,bv,bv,bv}); epilogue = 1 fma-with-abs per value.
// #pragma unroll 1 caps the live-register window (rounds 7/8: full unroll -> spill).

__global__ __launch_bounds__(256) void edge_mfma(const ushort* __restrict__ Z,
                                                 const int* __restrict__ ei,
                                                 const ushort* __restrict__ Wp2,
                                                 const float* __restrict__ abw,
                                                 const float2* __restrict__ G,
                                                 const float* __restrict__ mb2,
                                                 float* __restrict__ out, int E) {
    __shared__ __attribute__((aligned(16))) ushort As[256][32];
    __shared__ __attribute__((aligned(16))) ushort Bs[512][32];
    __shared__ float lin[256];
    int tid = threadIdx.x;
    int wid = tid >> 6, lane = tid & 63;
    int fr = lane & 15, qo = (lane >> 4) << 3;

    // stage W' (prescaled) into LDS
    for (int i = tid * 4; i < 512 * 32; i += 1024) {
        int n = i >> 5, k = i & 31;
        *(ushort4*)&Bs[n][k] = *(const ushort4*)(Wp2 + i);
    }
    float cb = abw[1056];
    int e0 = blockIdx.x * 256;
    {
        int e = e0 + tid;
        int r = 0, c = 0;
        if (e < E) { r = ei[e]; c = ei[E + e]; }
        uint4 z0 = *(const uint4*)(Z + r * 16);
        uint4 z1 = *(const uint4*)(Z + r * 16 + 8);
        uint4 z2 = *(const uint4*)(Z + c * 16);
        uint4 z3 = *(const uint4*)(Z + c * 16 + 8);
        *(uint4*)&As[tid][0]  = z0; *(uint4*)&As[tid][8]  = z1;
        *(uint4*)&As[tid][16] = z2; *(uint4*)&As[tid][24] = z3;
        float2 gr = G[r], gc = G[c];
        lin[tid] = gr.x + gc.y + cb;
    }
    __syncthreads();

    f16x8 a[4];
#pragma unroll
    for (int mt = 0; mt < 4; mt++) a[mt] = *(const f16x8*)&As[(wid * 4 + mt) * 16 + fr][qo];
    float pacc[4][4];
#pragma unroll
    for (int mt = 0; mt < 4; mt++)
#pragma unroll
        for (int j = 0; j < 4; j++) pacc[mt][j] = 0.f;
    float mb2v = mb2[0];

#pragma unroll 1
    for (int n = 0; n < 32; n++) {
        f16x8 bfr = *(const f16x8*)&Bs[n * 16 + fr][qo];
        int col = n * 16 + fr;
        float bv = abw[col], wv = abw[512 + col];
        f32x4 cin = {bv, bv, bv, bv};
#pragma unroll
        for (int mt = 0; mt < 4; mt++) {
            f32x4 c0 = __builtin_amdgcn_mfma_f32_16x16x32_f16(a[mt], bfr, cin, 0, 0, 0);
#pragma unroll
            for (int j = 0; j < 4; j++)
                pacc[mt][j] = fmaf(wv, fabsf(c0[j]), pacc[mt][j]);
        }
    }

#pragma unroll
    for (int mt = 0; mt < 4; mt++)
#pragma unroll
        for (int j = 0; j < 4; j++) {
            float p = pacc[mt][j];
            p += __shfl_xor(p, 1);
            p += __shfl_xor(p, 2);
            p += __shfl_xor(p, 4);
            p += __shfl_xor(p, 8);
            if (fr == 0) {
                int row = (wid * 4 + mt) * 16 + ((lane >> 4) << 2) + j;
                int e = e0 + row;
                if (e < E) out[e] = 1.f / (1.f + expf(-(0.25f * (lin[row] + p) + mb2v)));
            }
        }
}

// ---------------- launch ----------------

extern "C" void kernel_launch(void* const* d_in, const int* in_sizes, int n_in,
                              void* d_out, int out_size, void* d_ws, size_t ws_size,
                              hipStream_t stream) {
    const float* x     = (const float*)d_in[0];
    const int*   ei    = (const int*)d_in[1];
    const float* ew    = (const float*)d_in[2];
    const float* W0    = (const float*)d_in[3];
    const float* b0    = (const float*)d_in[4];
    const float* Wm    = (const float*)d_in[5];
    const float* bm    = (const float*)d_in[6];
    const float* Wl    = (const float*)d_in[7];
    const float* bl    = (const float*)d_in[8];
    const float* bn0_g = (const float*)d_in[9];
    const float* bn0_b = (const float*)d_in[10];
    const float* bnm_g = (const float*)d_in[11];
    const float* bnm_b = (const float*)d_in[12];
    const float* bno_g = (const float*)d_in[13];
    const float* bno_b = (const float*)d_in[14];
    const float* mW1   = (const float*)d_in[15];
    const float* mbn_g = (const float*)d_in[17];
    const float* mbn_b = (const float*)d_in[18];
    const float* mW2   = (const float*)d_in[19];
    const float* mb2   = (const float*)d_in[20];
    float* outp = (float*)d_out;

    char* ws = (char*)d_ws;
    unsigned long long* cw = (unsigned long long*)(ws + OFF_CW);
    int*    dout    = (int*)(ws + OFF_DOUT);
    float*  stats2  = (float*)(ws + OFF_STATS2);
    float*  sp8     = (float*)(ws + OFF_SP8);
    float*  MOM     = (float*)(ws + OFF_MOM);
    float*  st      = (float*)(ws + OFF_ST);
    float*  abw     = (float*)(ws + OFF_ABW);
    float*  w_in    = (float*)(ws + OFF_WIN);
    int*    offsets = (int*)(ws + OFF_OFFSETS);
    int2*   se      = (int2*)(ws + OFF_SE);
    int*    rank    = (int*)(ws + OFF_RANK);
    ushort* Wt      = (ushort*)(ws + OFF_WT);
    __half* bufQ    = (__half*)(ws + OFF_BUFQ);
    __half* bufP    = (__half*)(ws + OFF_BUFP);
    ushort* Wt2     = (ushort*)(ws + OFF_RANK + ALI_WT2);
    float*  bias2   = (float*)(ws + OFF_RANK + ALI_BIAS2);
    float2* G       = (float2*)(ws + OFF_RANK + ALI_G);
    float*  agg2    = (float*)(ws + OFF_BUFQ + ALI_TMP16);
    float*  tmp16   = (float*)(ws + OFF_BUFQ + ALI_TMP16);
    float*  hraw    = (float*)(ws + OFF_BUFQ + ALI_HRAW);
    ushort* Z       = (ushort*)(ws + OFF_BUFQ + ALI_Z);
    float*  aggz    = (float*)(ws + OFF_BUFQ + ALI_AGGZ);
    ushort* Wp2     = (ushort*)(ws + OFF_RANK + ALI_WT2);  // reuse Wt2 slot (dead by then)

    const int N = NNODES, E = NEDGES;

    hipMemsetAsync(ws, 0, ZERO_END, stream);

    // CSR build (rank-based) + weight preconvert
    hist_kernel<<<1024, 256, 0, stream>>>(ei, ew, cw, dout, rank, E);
    wconv<<<640, 256, 0, stream>>>(Wm, Wt);
    scan_kernel<<<1, 1024, 0, stream>>>(cw, offsets, w_in, N);
    scatter_kernel<<<1024, 256, 0, stream>>>(ei, ew, offsets, rank, se, E);

    // ---- layer 0 ----
    colstats_wr<<<64, 256, 0, stream>>>(x, stats2 + 0 * 512, 2, N);
    bn_finalize<<<1, 256, 0, stream>>>(stats2 + 0 * 512, bn0_g, bn0_b, st, 2, N);
    spmm_small<<<(N + 127) / 128, 256, 0, stream>>>(x, se, offsets, agg2, 2, N, 0);
    layer0_fin<<<512, 256, 0, stream>>>(agg2, w_in, st, W0, b0, bufP, sp8 + 0 * 8192, N);

    // ---- 10 mid layers ----
    for (int i = 0; i < 10; i++) {
        bnw<<<64, 256, 0, stream>>>(sp8 + i * 8192, bnm_g + i * 256, bnm_b + i * 256,
                                    Wt + i * 65536, bm + i * 256, Wt2, bias2, N);
        gemm_mfma<<<dim3((N + 127) / 128, 2), 256, 0, stream>>>(bufP, Wt2, bias2, bufQ, N);
        spmm_f16w<<<2048, 256, 0, stream>>>(bufQ, se, offsets, bufP,
                                            sp8 + (i + 1) * 8192, N);
    }

    // ---- last GCN layer (256 -> 16) ----
    bn_finalize16<<<1, 256, 0, stream>>>(sp8 + 10 * 8192, bnm_g + 10 * 256,
                                         bnm_b + 10 * 256, st, N);
    gemm16<<<(N + 15) / 16, 256, 0, stream>>>(bufP, Wl, bl, st, tmp16, N);
    spmm_small<<<(N + 15) / 16, 256, 0, stream>>>(tmp16, se, offsets, hraw, 16, N, 1);

    // ---- final BN -> z (fp16) ----
    colstats_wr<<<64, 256, 0, stream>>>(hraw, stats2 + 1 * 512, 16, N);
    bn_finalize<<<1, 256, 0, stream>>>(stats2 + 1 * 512, bno_g, bno_b, st, 16, N);
    zprep<<<(N * 16 + 255) / 256, 256, 0, stream>>>(hraw, st, Z, N * 16);

    // ---- analytic edge-MLP BN stats + prescaled weights ----
    aggz_spmm<<<(N + 15) / 16, 256, 0, stream>>>(Z, se, offsets, aggz, N);
    zmom<<<256, 256, 0, stream>>>(Z, aggz, dout, cw, MOM, N);
    mlp_ab<<<1, 256, 0, stream>>>(MOM, mW1, mbn_g, mbn_b, mW2, abw, Wp2, E);
    gprep<<<(N + 255) / 256, 256, 0, stream>>>(Z, abw, G, N);

    // ---- edge MLP output (MFMA, bias-in-C, abs-trick) ----
    edge_mfma<<<(E + 255) / 256, 256, 0, stream>>>(Z, ei, Wp2, abw, G, mb2, outp, E);
}

// Round 13
// 1406.641 us; speedup vs baseline: 1.1525x; 1.0509x over previous
//
#include <hip/hip_runtime.h>
#include <hip/hip_bf16.h>
#include <hip/hip_fp16.h>
#include <math.h>

#define NNODES 50000
#define NEDGES 800000

// ---------------- workspace layout (bytes) ----------------
#define OFF_CW       0ull                      // u64[50000] packed count|w_in (zeroed)
#define OFF_DOUT     401408ull                 // int[50000] (zeroed)
#define OFF_STATS2   602112ull                 // float[2*512] (zeroed)
#define OFF_SP8      606208ull                 // float[11*16*512] (zeroed)
#define OFF_MOM      966656ull                 // float[16*800] (zeroed)
#define ZERO_END     1017856ull
#define OFF_ST       1017856ull                // float[512]
#define OFF_ABW      1019904ull                // float[1536]: bb[512]|ww[512]|g32[32]|cb
#define OFF_WIN      1026048ull                // float[50000]
#define OFF_OFFSETS  1226752ull                // int[50001]
#define OFF_SE       1427456ull                // int2[800000] packed (srow, ew)
#define OFF_RANK     7827456ull                // int[800000]; aliased after scatter:
#define ALI_WT2      0ull                      //   ushort[256*256] (later Wp2)
#define ALI_BIAS2    131072ull                 //   float[256]
#define ALI_G        132096ull                 //   float2[50000]
#define OFF_WT       11027456ull               // ushort[10*256*256] fp16 W (transposed)
#define OFF_BUFQ     12371968ull               // half[50000*256]
#define OFF_BUFP     37971968ull               // half[50000*256]
// aliases inside dead BUFQ (after 10th spmm; agg2 dead before 1st gemm):
#define ALI_TMP16    0ull                      // float[50000*16]
#define ALI_HRAW     3276800ull                // float[50000*16]
#define ALI_Z        6553600ull                // ushort[50000*16]
#define ALI_AGGZ     8388608ull                // float[50000*16]

typedef __attribute__((ext_vector_type(8))) _Float16 f16x8;
typedef __attribute__((ext_vector_type(4))) float f32x4;

union H4 { ushort4 u; __half h[4]; };
union US8 { uint4 u; __half h[8]; };
union HU { ushort u; __half h; };

static __device__ inline ushort f2h(float f) {
    HU cv; cv.h = __float2half(f); return cv.u;
}
static __device__ inline float h2f(ushort u) {
    HU cv; cv.u = u; return __half2float(cv.h);
}

// ---------------- preprocessing ----------------

__global__ void hist_kernel(const int* __restrict__ ei, const float* __restrict__ ew,
                            unsigned long long* __restrict__ cw, int* __restrict__ dout,
                            int* __restrict__ rank, int E) {
    for (int i = blockIdx.x * blockDim.x + threadIdx.x; i < E; i += gridDim.x * blockDim.x) {
        int r = ei[i];
        int c = ei[E + i];
        unsigned long long pack = (1ull << 40) |
            (unsigned long long)__float2uint_rn(ew[i] * 1048576.f);
        unsigned long long old = atomicAdd(&cw[c], pack);
        rank[i] = (int)(old >> 40);
        atomicAdd(&dout[r], 1);
    }
}

__global__ void scan_kernel(const unsigned long long* __restrict__ cw,
                            int* __restrict__ offsets, float* __restrict__ w_in, int N) {
    __shared__ int wsum[16];
    __shared__ int carry_s;
    int tid = threadIdx.x;
    int lane = tid & 63, w = tid >> 6;
    if (tid == 0) carry_s = 0;
    __syncthreads();
    for (int base = 0; base < N; base += 1024) {
        int v = 0;
        if (base + tid < N) {
            unsigned long long cv = cw[base + tid];
            v = (int)(cv >> 40);
            w_in[base + tid] = (float)(cv & 0xFFFFFFFFFFull) * (1.f / 1048576.f);
        }
        int x = v;
#pragma unroll
        for (int off = 1; off < 64; off <<= 1) {
            int y = __shfl_up(x, off);
            if (lane >= off) x += y;
        }
        if (lane == 63) wsum[w] = x;
        __syncthreads();
        if (w == 0 && lane < 16) {
            int s = wsum[lane];
#pragma unroll
            for (int off = 1; off < 16; off <<= 1) {
                int y = __shfl_up(s, off);
                if (lane >= off) s += y;
            }
            wsum[lane] = s;
        }
        __syncthreads();
        int wbase = (w > 0) ? wsum[w - 1] : 0;
        int incl = carry_s + wbase + x;
        if (base + tid < N) offsets[base + tid] = incl - v;
        __syncthreads();
        if (tid == 0) carry_s += wsum[15];
        __syncthreads();
    }
    if (tid == 0) offsets[N] = carry_s;
}

__global__ void scatter_kernel(const int* __restrict__ ei, const float* __restrict__ ew,
                               const int* __restrict__ offsets, const int* __restrict__ rank,
                               int2* __restrict__ se, int E) {
    for (int i = blockIdx.x * blockDim.x + threadIdx.x; i < E; i += gridDim.x * blockDim.x) {
        int c = ei[E + i];
        int p = offsets[c] + rank[i];
        se[p] = make_int2(ei[i], __float_as_int(ew[i]));
    }
}

// ---------------- weight preconvert: Wt[n][k] = fp16(Wm[k][n]) ----------------

__global__ __launch_bounds__(256) void wconv(const float* __restrict__ Wm,
                                             ushort* __restrict__ Wt) {
    __shared__ float tile[32][33];
    int b = blockIdx.x;
    int layer = b >> 6, t = b & 63;
    int tk = (t >> 3) << 5, tn = (t & 7) << 5;
    int tid = threadIdx.x;
    int r = tid >> 5, c = tid & 31;
    const float* W = Wm + layer * 65536;
#pragma unroll
    for (int i = 0; i < 4; i++) tile[r + i * 8][c] = W[(tk + r + i * 8) * 256 + tn + c];
    __syncthreads();
#pragma unroll
    for (int i = 0; i < 4; i++) {
        int n = tn + r + i * 8, k = tk + c;
        Wt[layer * 65536 + n * 256 + k] = f2h(tile[c][r + i * 8]);
    }
}

// ---------------- small-C column stats (wave-reduced) ----------------

__global__ __launch_bounds__(256) void colstats_wr(const float* __restrict__ h,
                                                   float* __restrict__ sums, int C, int M) {
    int gtid = blockIdx.x * blockDim.x + threadIdx.x;
    int lane = threadIdx.x & 63;
    int c = gtid % C;
    int r = gtid / C;
    int stride = (gridDim.x * blockDim.x) / C;
    float s = 0.f, q = 0.f;
    for (; r < M; r += stride) {
        float v = h[r * C + c];
        s += v; q += v * v;
    }
    for (int m = 32; m >= C; m >>= 1) {
        s += __shfl_xor(s, m);
        q += __shfl_xor(q, m);
    }
    if (lane < C) {
        atomicAdd(&sums[c], s);
        atomicAdd(&sums[C + c], q);
    }
}

__global__ void bn_finalize(const float* __restrict__ sums, const float* __restrict__ g,
                            const float* __restrict__ b, float* __restrict__ st, int C, int M) {
    int c = threadIdx.x;
    if (c >= C) return;
    float mean = sums[c] / (float)M;
    float var  = sums[C + c] / (float)M - mean * mean;
    float sc = g[c] * rsqrtf(var + 1e-5f);
    st[c] = sc;
    st[C + c] = b[c] - mean * sc;
}

__global__ void bn_finalize16(const float* __restrict__ sp, const float* __restrict__ g,
                              const float* __restrict__ b, float* __restrict__ st, int M) {
    int c = threadIdx.x;
    float s = 0.f, q = 0.f;
#pragma unroll
    for (int p = 0; p < 16; p++) { s += sp[p * 512 + c]; q += sp[p * 512 + 256 + c]; }
    float mean = s / (float)M;
    float var  = q / (float)M - mean * mean;
    float sc = g[c] * rsqrtf(var + 1e-5f);
    st[c] = sc;
    st[256 + c] = b[c] - mean * sc;
}

// ---------------- per-layer weight fold: Wt2 = s∘Wt (fp16), bias2 = bias + t@W ----------------

__global__ __launch_bounds__(256) void bnw(const float* __restrict__ sp,
                                           const float* __restrict__ g,
                                           const float* __restrict__ b,
                                           const ushort* __restrict__ Wt,
                                           const float* __restrict__ bias,
                                           ushort* __restrict__ Wt2,
                                           float* __restrict__ bias2, int M) {
    __shared__ float st_s[512];
    int tid = threadIdx.x;
    {
        float s = 0.f, q = 0.f;
#pragma unroll
        for (int p = 0; p < 16; p++) { s += sp[p * 512 + tid]; q += sp[p * 512 + 256 + tid]; }
        float invM = 1.f / (float)M;
        float mean = s * invM;
        float var  = q * invM - mean * mean;
        float sc = g[tid] * rsqrtf(var + 1e-5f);
        st_s[tid] = sc;
        st_s[256 + tid] = b[tid] - mean * sc;
    }
    __syncthreads();
    int n = blockIdx.x * 4 + (tid >> 6);
    int k4 = (tid & 63) << 2;
    ushort4 w4 = *(const ushort4*)(Wt + n * 256 + k4);
    float4 s4 = *(const float4*)(st_s + k4);
    float4 t4 = *(const float4*)(st_s + 256 + k4);
    float w0 = h2f(w4.x), w1 = h2f(w4.y), w2 = h2f(w4.z), w3 = h2f(w4.w);
    ushort4 o;
    o.x = f2h(w0 * s4.x); o.y = f2h(w1 * s4.y);
    o.z = f2h(w2 * s4.z); o.w = f2h(w3 * s4.w);
    *(ushort4*)(Wt2 + n * 256 + k4) = o;
    float part = w0 * t4.x + w1 * t4.y + w2 * t4.z + w3 * t4.w;
#pragma unroll
    for (int m = 1; m < 64; m <<= 1) part += __shfl_xor(part, m);
    if ((tid & 63) == 0) bias2[n] = bias[n] + part;
}

// ---------------- MFMA GEMM (fp16, pre-folded BN): out = H@Wt2 + bias2 ----------------
// round-9 structure + register-staged prefetch of k+1.
// NOTE: B addresses must include n0 (round-12 bug: missing n0 -> wrong columns).

__global__ __launch_bounds__(256) void gemm_mfma(const __half* __restrict__ H,
                                                 const ushort* __restrict__ Wt2,
                                                 const float* __restrict__ bias2,
                                                 __half* __restrict__ out, int M) {
    __shared__ __attribute__((aligned(16))) ushort Ah[128][40];
    __shared__ __attribute__((aligned(16))) ushort Bh[128][40];
    int tid = threadIdx.x;
    int wid = tid >> 6, lane = tid & 63;
    int m0 = blockIdx.x * 128;
    int n0 = blockIdx.y * 128;
    const ushort* Hu = (const ushort*)H;

    f32x4 acc[2][8];
#pragma unroll
    for (int m = 0; m < 2; m++)
#pragma unroll
        for (int n = 0; n < 8; n++) acc[m][n] = (f32x4){0.f, 0.f, 0.f, 0.f};

    int sr = tid >> 3;
    int kq = (tid & 7) << 2;
    int fr = lane & 15;
    int qo = (lane >> 4) << 3;
    int mrow = wid << 5;

    // A-row / B-row base addresses
    int grs[4];
#pragma unroll
    for (int t = 0; t < 4; t++) {
        int gr = m0 + sr + t * 32; if (gr >= M) gr = M - 1;
        grs[t] = gr;
    }

    ushort4 av[4], bv[4];
#pragma unroll
    for (int t = 0; t < 4; t++) {
        av[t] = *(const ushort4*)(Hu + grs[t] * 256 + kq);
        bv[t] = *(const ushort4*)(Wt2 + (n0 + sr + t * 32) * 256 + kq);
    }

    for (int k0 = 0; k0 < 256; k0 += 32) {
#pragma unroll
        for (int t = 0; t < 4; t++) {
            int r = sr + t * 32;
            *(ushort4*)&Ah[r][kq] = av[t];
            *(ushort4*)&Bh[r][kq] = bv[t];
        }
        __syncthreads();

        // prefetch next k-chunk while MFMAs run
        if (k0 + 32 < 256) {
#pragma unroll
            for (int t = 0; t < 4; t++) {
                av[t] = *(const ushort4*)(Hu + grs[t] * 256 + k0 + 32 + kq);
                bv[t] = *(const ushort4*)(Wt2 + (n0 + sr + t * 32) * 256 + k0 + 32 + kq);
            }
        }

        f16x8 a0 = *(const f16x8*)&Ah[mrow + fr][qo];
        f16x8 a1 = *(const f16x8*)&Ah[mrow + 16 + fr][qo];
#pragma unroll
        for (int nt = 0; nt < 8; nt++) {
            f16x8 bb = *(const f16x8*)&Bh[nt * 16 + fr][qo];
            acc[0][nt] = __builtin_amdgcn_mfma_f32_16x16x32_f16(a0, bb, acc[0][nt], 0, 0, 0);
            acc[1][nt] = __builtin_amdgcn_mfma_f32_16x16x32_f16(a1, bb, acc[1][nt], 0, 0, 0);
        }
        __syncthreads();
    }

#pragma unroll
    for (int mt = 0; mt < 2; mt++) {
        int gmb = m0 + mrow + mt * 16 + ((lane >> 4) << 2);
#pragma unroll
        for (int nt = 0; nt < 8; nt++) {
            int gn = n0 + nt * 16 + fr;
            float bvv = bias2[gn];
#pragma unroll
            for (int j = 0; j < 4; j++) {
                int gm = gmb + j;
                if (gm < M) out[gm * 256 + gn] = __float2half(acc[mt][nt][j] + bvv);
            }
        }
    }
}

// ---------------- SpMM fp16: 2 edges/wave, 16B loads, fused column stats ----------------

__global__ __launch_bounds__(256) void spmm_f16w(const __half* __restrict__ T,
                                                 const int2* __restrict__ se,
                                                 const int* __restrict__ off,
                                                 __half* __restrict__ outp,
                                                 float* __restrict__ sp, int N) {
    __shared__ float red[4][512];
    int tid = threadIdx.x;
    int wid = tid >> 6, lane = tid & 63;
    int hh = lane >> 5;
    int li = lane & 31;
    int colb = li << 3;
    const ushort* Tu = (const ushort*)T;
    ushort* Ou = (ushort*)outp;
    float cs[8] = {0, 0, 0, 0, 0, 0, 0, 0}, cq[8] = {0, 0, 0, 0, 0, 0, 0, 0};
    int gw = blockIdx.x * 4 + wid, nw = gridDim.x * 4;
    for (int n = gw; n < N; n += nw) {
        int e0 = off[n], e1 = off[n + 1];
        float acc[8] = {0, 0, 0, 0, 0, 0, 0, 0};
        int e = e0;
        for (; e + 7 < e1; e += 8) {
            int2 s[4]; US8 v[4];
#pragma unroll
            for (int i = 0; i < 4; i++) s[i] = se[e + 2 * i + hh];
#pragma unroll
            for (int i = 0; i < 4; i++) v[i].u = *(const uint4*)(Tu + s[i].x * 256 + colb);
#pragma unroll
            for (int i = 0; i < 4; i++) {
                float w = __int_as_float(s[i].y);
#pragma unroll
                for (int j = 0; j < 8; j++) acc[j] += w * __half2float(v[i].h[j]);
            }
        }
        for (; e < e1; e += 2) {
            if (e + hh < e1) {
                int2 s = se[e + hh];
                float w = __int_as_float(s.y);
                US8 v; v.u = *(const uint4*)(Tu + s.x * 256 + colb);
#pragma unroll
                for (int j = 0; j < 8; j++) acc[j] += w * __half2float(v.h[j]);
            }
        }
        US8 o;
#pragma unroll
        for (int j = 0; j < 8; j++) {
            float other = __shfl(acc[j], lane ^ 32, 64);
            float s = fmaxf(acc[j] + other, 0.f);
            o.h[j] = __float2half(s);
            if (hh == 0) { cs[j] += s; cq[j] += s * s; }
        }
        if (hh == 0) *(uint4*)(Ou + n * 256 + colb) = o.u;
    }
    if (hh == 0) {
#pragma unroll
        for (int j = 0; j < 8; j++) {
            red[wid][colb + j] = cs[j];
            red[wid][256 + colb + j] = cq[j];
        }
    }
    __syncthreads();
    float* dst = sp + (blockIdx.x & 15) * 512;
    for (int i = tid; i < 512; i += 256)
        atomicAdd(&dst[i], red[0][i] + red[1][i] + red[2][i] + red[3][i]);
}

__global__ __launch_bounds__(256) void spmm_small(const float* __restrict__ T,
                                                  const int2* __restrict__ se,
                                                  const int* __restrict__ off,
                                                  float* __restrict__ out,
                                                  int C, int N, int relu) {
    int npb = blockDim.x / C;
    int local = threadIdx.x / C;
    int c = threadIdx.x % C;
    int n = blockIdx.x * npb + local;
    if (n >= N) return;
    int e0 = off[n], e1 = off[n + 1];
    float acc = 0.f;
    for (int e = e0; e < e1; ++e) {
        int2 s = se[e];
        acc += __int_as_float(s.y) * T[s.x * C + c];
    }
    if (relu) acc = fmaxf(acc, 0.f);
    out[n * C + c] = acc;
}

// ---------------- layer 0 finalize + fused column stats ----------------

__global__ __launch_bounds__(256) void layer0_fin(const float* __restrict__ agg2,
                                                  const float* __restrict__ w_in,
                                                  const float* __restrict__ st,
                                                  const float* __restrict__ W0,
                                                  const float* __restrict__ b0,
                                                  __half* __restrict__ h,
                                                  float* __restrict__ sp, int N) {
    int j = threadIdx.x;
    float w0j = W0[j], w1j = W0[256 + j], b0j = b0[j];
    float s0 = st[0], s1 = st[1], t0 = st[2], t1 = st[3];
    float cs = 0.f, cq = 0.f;
    for (int n = blockIdx.x; n < N; n += gridDim.x) {
        float wi = w_in[n];
        float a0 = agg2[n * 2 + 0] * s0 + wi * t0;
        float a1 = agg2[n * 2 + 1] * s1 + wi * t1;
        float v = fmaxf(a0 * w0j + a1 * w1j + wi * b0j, 0.f);
        h[n * 256 + j] = __float2half(v);
        cs += v; cq += v * v;
    }
    float* dst = sp + (blockIdx.x & 15) * 512;
    atomicAdd(&dst[j], cs);
    atomicAdd(&dst[256 + j], cq);
}

// ---------------- last GCN linear: [M,256]f16 x [256,16] ----------------

__global__ __launch_bounds__(256) void gemm16(const __half* __restrict__ H,
                                              const float* __restrict__ Wl,
                                              const float* __restrict__ bl,
                                              const float* __restrict__ st,
                                              float* __restrict__ out, int M) {
    __shared__ float Hs[16][256];
    __shared__ float Ws[256][16];
    int tid = threadIdx.x;
    int n0 = blockIdx.x << 4;
    const ushort* Hu = (const ushort*)H;
    for (int i = tid; i < 4096; i += 256) Ws[i >> 4][i & 15] = Wl[i];
    for (int i = tid; i < 4096; i += 256) {
        int r = i >> 8, k = i & 255;
        int n = n0 + r;
        float hv = 0.f;
        if (n < M) hv = h2f(Hu[n * 256 + k]) * st[k] + st[256 + k];
        Hs[r][k] = hv;
    }
    __syncthreads();
    int r = tid >> 4, j = tid & 15;
    float acc = bl[j];
    for (int k = 0; k < 256; k++) acc += Hs[r][k] * Ws[k][j];
    if (n0 + r < M) out[(n0 + r) * 16 + j] = acc;
}

// ---------------- z prep: z = fp16(bn(hraw)) ----------------

__global__ void zprep(const float* __restrict__ hraw, const float* __restrict__ st,
                      ushort* __restrict__ Z, int NE) {
    int i = blockIdx.x * blockDim.x + threadIdx.x;
    if (i >= NE) return;
    int c = i & 15;
    Z[i] = f2h(hraw[i] * st[c] + st[16 + c]);
}

// ---------------- unweighted 16-wide spmm ----------------

__global__ __launch_bounds__(256) void aggz_spmm(const ushort* __restrict__ Z,
                                                 const int2* __restrict__ se,
                                                 const int* __restrict__ off,
                                                 float* __restrict__ aggz, int N) {
    int local = threadIdx.x >> 4;
    int c = threadIdx.x & 15;
    int n = blockIdx.x * 16 + local;
    if (n >= N) return;
    int e0 = off[n], e1 = off[n + 1];
    float acc = 0.f;
    for (int e = e0; e < e1; ++e) acc += h2f(Z[se[e].x * 16 + c]);
    aggz[n * 16 + c] = acc;
}

// ---------------- node moments: P, R, M, Sdout, Sdin ----------------

__global__ __launch_bounds__(256) void zmom(const ushort* __restrict__ Z,
                                            const float* __restrict__ aggz,
                                            const int* __restrict__ dout,
                                            const unsigned long long* __restrict__ cw,
                                            float* __restrict__ MOM, int N) {
    __shared__ float zs[128][17];
    __shared__ float az[128][17];
    __shared__ float dw[128][2];
    int tid = threadIdx.x;
    int i = tid >> 4, j = tid & 15;
    float p = 0.f, r = 0.f, m = 0.f, sdo = 0.f, sdi = 0.f;
    for (int base = blockIdx.x * 128; base < N; base += gridDim.x * 128) {
        int cnt = N - base; if (cnt > 128) cnt = 128;
        for (int t = tid; t < 2048; t += 256) {
            int n = t >> 4, c = t & 15;
            if (n < cnt) {
                zs[n][c] = h2f(Z[(base + n) * 16 + c]);
                az[n][c] = aggz[(base + n) * 16 + c];
            } else { zs[n][c] = 0.f; az[n][c] = 0.f; }
        }
        for (int t = tid; t < 128; t += 256) {
            if (t < cnt) {
                dw[t][0] = (float)dout[base + t];
                dw[t][1] = (float)(int)(cw[base + t] >> 40);
            } else { dw[t][0] = 0.f; dw[t][1] = 0.f; }
        }
        __syncthreads();
        for (int n = 0; n < 128; n++) {
            float zi = zs[n][i], zj = zs[n][j];
            float d0 = dw[n][0], d1 = dw[n][1];
            float zz = zi * zj;
            p += d0 * zz;
            r += d1 * zz;
            m += az[n][i] * zj;
            if (i == 0) { sdo += d0 * zj; sdi += d1 * zj; }
        }
        __syncthreads();
    }
    float* dst = MOM + (blockIdx.x & 15) * 800;
    atomicAdd(&dst[tid], p);
    atomicAdd(&dst[256 + tid], r);
    atomicAdd(&dst[512 + tid], m);
    if (i == 0) { atomicAdd(&dst[768 + j], sdo); atomicAdd(&dst[784 + j], sdi); }
}

// ---------------- analytic edge-MLP BN affine + prescaled W' + linear-term vector ----------------
// abw: [0..511] bias' | [512..1023] w | [1024..1055] g32 | [1056] cbeta

__global__ __launch_bounds__(256) void mlp_ab(const float* __restrict__ MOM,
                                              const float* __restrict__ mW1,
                                              const float* __restrict__ g,
                                              const float* __restrict__ b,
                                              const float* __restrict__ mW2,
                                              float* __restrict__ abw,
                                              ushort* __restrict__ Wp2, int E) {
    __shared__ float P[256], R[256], Mm[256], Sdo[16], Sdi[16];
    __shared__ float gsh[33];
    int tid = threadIdx.x;
    if (tid < 33) gsh[tid] = 0.f;
    float sp = 0.f, sr = 0.f, sm = 0.f;
#pragma unroll
    for (int q = 0; q < 16; q++) {
        sp += MOM[q * 800 + tid];
        sr += MOM[q * 800 + 256 + tid];
        sm += MOM[q * 800 + 512 + tid];
    }
    P[tid] = sp; R[tid] = sr; Mm[tid] = sm;
    if (tid < 16) {
        float a = 0.f, c = 0.f;
#pragma unroll
        for (int q = 0; q < 16; q++) { a += MOM[q * 800 + 768 + tid]; c += MOM[q * 800 + 784 + tid]; }
        Sdo[tid] = a; Sdi[tid] = c;
    }
    __syncthreads();
    int j = tid;
    float A[16], B[16];
#pragma unroll
    for (int k = 0; k < 16; k++) { A[k] = mW1[k * 256 + j]; B[k] = mW1[(16 + k) * 256 + j]; }
    float apa = 0.f, brb = 0.f, amb = 0.f, bpb = 0.f, ara = 0.f, bma = 0.f;
    float aso = 0.f, bso = 0.f, asi = 0.f, bsi = 0.f;
    for (int i2 = 0; i2 < 16; i2++) {
        float Ai = A[i2], Bi = B[i2];
        aso += Ai * Sdo[i2]; bso += Bi * Sdo[i2];
        asi += Ai * Sdi[i2]; bsi += Bi * Sdi[i2];
#pragma unroll
        for (int k = 0; k < 16; k++) {
            float Pik = P[i2 * 16 + k], Rik = R[i2 * 16 + k], Mik = Mm[i2 * 16 + k];
            apa += Ai * Pik * A[k]; brb += Bi * Rik * B[k]; amb += Ai * Mik * B[k];
            bpb += Bi * Pik * B[k]; ara += Ai * Rik * A[k]; bma += Bi * Mik * A[k];
        }
    }
    float invE = 1.f / (float)E;
    float mu1 = (aso + bsi) * invE;
    float mu2 = (bso + asi) * invE;
    float e21 = (apa + brb + 2.f * amb) * invE;
    float e22 = (bpb + ara + 2.f * bma) * invE;
    float a1 = g[j] * rsqrtf(e21 - mu1 * mu1 + 1e-5f);
    float a2 = g[j] * rsqrtf(e22 - mu2 * mu2 + 1e-5f);
    float b1p = b[j] - mu1 * a1;
    float b2p = b[j] - mu2 * a2;
    float w = mW2[j];
    abw[j] = b1p; abw[256 + j] = b2p;
    abw[512 + j] = w; abw[768 + j] = w;
#pragma unroll
    for (int k = 0; k < 16; k++) {
        Wp2[j * 32 + k]              = f2h(a1 * A[k]);
        Wp2[j * 32 + 16 + k]         = f2h(a1 * B[k]);
        Wp2[(256 + j) * 32 + k]      = f2h(a2 * B[k]);
        Wp2[(256 + j) * 32 + 16 + k] = f2h(a2 * A[k]);
    }
#pragma unroll
    for (int k = 0; k < 16; k++) {
        atomicAdd(&gsh[k],      w * (a1 * A[k] + a2 * B[k]));
        atomicAdd(&gsh[16 + k], w * (a1 * B[k] + a2 * A[k]));
    }
    atomicAdd(&gsh[32], w * (b1p + b2p));
    __syncthreads();
    if (tid < 32) abw[1024 + tid] = gsh[tid];
    if (tid == 0) abw[1056] = gsh[32];
}

// ---------------- per-node linear term ----------------

__global__ __launch_bounds__(256) void gprep(const ushort* __restrict__ Z,
                                             const float* __restrict__ abw,
                                             float2* __restrict__ G, int N) {
    __shared__ float gs[32];
    if (threadIdx.x < 32) gs[threadIdx.x] = abw[1024 + threadIdx.x];
    __syncthreads();
    int n = blockIdx.x * blockDim.x + threadIdx.x;
    if (n >= N) return;
    float g1 = 0.f, g2 = 0.f;
#pragma unroll
    for (int k = 0; k < 16; k++) {
        float z = h2f(Z[n * 16 + k]);
        g1 += z * gs[k];
        g2 += z * gs[16 + k];
    }
    G[n] = make_float2(g1, g2);
}

// ---------------- edge MLP output: MFMA (bias in C-operand) + abs-trick ----------------
// w*relu(s) = 0.5*(w*s + w*|s|); linear part in lin[]; bias added by matrix unit
// (C_in = {bv,bv,bv,bv}); epilogue = 1 fma-with-abs per value.
// unroll 2: two iteration streams in flight (full unroll -> spill, unroll 1 -> serial).

__global__ __launch_bounds__(256) void edge_mfma(const ushort* __restrict__ Z,
                                                 const int* __restrict__ ei,
                                                 const ushort* __restrict__ Wp2,
                                                 const float* __restrict__ abw,
                                                 const float2* __restrict__ G,
                                                 const float* __restrict__ mb2,
                                                 float* __restrict__ out, int E) {
    __shared__ __attribute__((aligned(16))) ushort As[256][32];
    __shared__ __attribute__((aligned(16))) ushort Bs[512][32];
    __shared__ float lin[256];
    int tid = threadIdx.x;
    int wid = tid >> 6, lane = tid & 63;
    int fr = lane & 15, qo = (lane >> 4) << 3;

    // stage W' (prescaled) into LDS
    for (int i = tid * 4; i < 512 * 32; i += 1024) {
        int n = i >> 5, k = i & 31;
        *(ushort4*)&Bs[n][k] = *(const ushort4*)(Wp2 + i);
    }
    float cb = abw[1056];
    int e0 = blockIdx.x * 256;
    {
        int e = e0 + tid;
        int r = 0, c = 0;
        if (e < E) { r = ei[e]; c = ei[E + e]; }
        uint4 z0 = *(const uint4*)(Z + r * 16);
        uint4 z1 = *(const uint4*)(Z + r * 16 + 8);
        uint4 z2 = *(const uint4*)(Z + c * 16);
        uint4 z3 = *(const uint4*)(Z + c * 16 + 8);
        *(uint4*)&As[tid][0]  = z0; *(uint4*)&As[tid][8]  = z1;
        *(uint4*)&As[tid][16] = z2; *(uint4*)&As[tid][24] = z3;
        float2 gr = G[r], gc = G[c];
        lin[tid] = gr.x + gc.y + cb;
    }
    __syncthreads();

    f16x8 a[4];
#pragma unroll
    for (int mt = 0; mt < 4; mt++) a[mt] = *(const f16x8*)&As[(wid * 4 + mt) * 16 + fr][qo];
    float pacc[4][4];
#pragma unroll
    for (int mt = 0; mt < 4; mt++)
#pragma unroll
        for (int j = 0; j < 4; j++) pacc[mt][j] = 0.f;
    float mb2v = mb2[0];

#pragma unroll 2
    for (int n = 0; n < 32; n++) {
        f16x8 bfr = *(const f16x8*)&Bs[n * 16 + fr][qo];
        int col = n * 16 + fr;
        float bv = abw[col], wv = abw[512 + col];
        f32x4 cin = {bv, bv, bv, bv};
#pragma unroll
        for (int mt = 0; mt < 4; mt++) {
            f32x4 c0 = __builtin_amdgcn_mfma_f32_16x16x32_f16(a[mt], bfr, cin, 0, 0, 0);
#pragma unroll
            for (int j = 0; j < 4; j++)
                pacc[mt][j] = fmaf(wv, fabsf(c0[j]), pacc[mt][j]);
        }
    }

#pragma unroll
    for (int mt = 0; mt < 4; mt++)
#pragma unroll
        for (int j = 0; j < 4; j++) {
            float p = pacc[mt][j];
            p += __shfl_xor(p, 1);
            p += __shfl_xor(p, 2);
            p += __shfl_xor(p, 4);
            p += __shfl_xor(p, 8);
            if (fr == 0) {
                int row = (wid * 4 + mt) * 16 + ((lane >> 4) << 2) + j;
                int e = e0 + row;
                if (e < E) out[e] = 1.f / (1.f + expf(-(0.25f * (lin[row] + p) + mb2v)));
            }
        }
}

// ---------------- launch ----------------

extern "C" void kernel_launch(void* const* d_in, const int* in_sizes, int n_in,
                              void* d_out, int out_size, void* d_ws, size_t ws_size,
                              hipStream_t stream) {
    const float* x     = (const float*)d_in[0];
    const int*   ei    = (const int*)d_in[1];
    const float* ew    = (const float*)d_in[2];
    const float* W0    = (const float*)d_in[3];
    const float* b0    = (const float*)d_in[4];
    const float* Wm    = (const float*)d_in[5];
    const float* bm    = (const float*)d_in[6];
    const float* Wl    = (const float*)d_in[7];
    const float* bl    = (const float*)d_in[8];
    const float* bn0_g = (const float*)d_in[9];
    const float* bn0_b = (const float*)d_in[10];
    const float* bnm_g = (const float*)d_in[11];
    const float* bnm_b = (const float*)d_in[12];
    const float* bno_g = (const float*)d_in[13];
    const float* bno_b = (const float*)d_in[14];
    const float* mW1   = (const float*)d_in[15];
    const float* mbn_g = (const float*)d_in[17];
    const float* mbn_b = (const float*)d_in[18];
    const float* mW2   = (const float*)d_in[19];
    const float* mb2   = (const float*)d_in[20];
    float* outp = (float*)d_out;

    char* ws = (char*)d_ws;
    unsigned long long* cw = (unsigned long long*)(ws + OFF_CW);
    int*    dout    = (int*)(ws + OFF_DOUT);
    float*  stats2  = (float*)(ws + OFF_STATS2);
    float*  sp8     = (float*)(ws + OFF_SP8);
    float*  MOM     = (float*)(ws + OFF_MOM);
    float*  st      = (float*)(ws + OFF_ST);
    float*  abw     = (float*)(ws + OFF_ABW);
    float*  w_in    = (float*)(ws + OFF_WIN);
    int*    offsets = (int*)(ws + OFF_OFFSETS);
    int2*   se      = (int2*)(ws + OFF_SE);
    int*    rank    = (int*)(ws + OFF_RANK);
    ushort* Wt      = (ushort*)(ws + OFF_WT);
    __half* bufQ    = (__half*)(ws + OFF_BUFQ);
    __half* bufP    = (__half*)(ws + OFF_BUFP);
    ushort* Wt2     = (ushort*)(ws + OFF_RANK + ALI_WT2);
    float*  bias2   = (float*)(ws + OFF_RANK + ALI_BIAS2);
    float2* G       = (float2*)(ws + OFF_RANK + ALI_G);
    float*  agg2    = (float*)(ws + OFF_BUFQ + ALI_TMP16);
    float*  tmp16   = (float*)(ws + OFF_BUFQ + ALI_TMP16);
    float*  hraw    = (float*)(ws + OFF_BUFQ + ALI_HRAW);
    ushort* Z       = (ushort*)(ws + OFF_BUFQ + ALI_Z);
    float*  aggz    = (float*)(ws + OFF_BUFQ + ALI_AGGZ);
    ushort* Wp2     = (ushort*)(ws + OFF_RANK + ALI_WT2);  // reuse Wt2 slot (dead by then)

    const int N = NNODES, E = NEDGES;

    hipMemsetAsync(ws, 0, ZERO_END, stream);

    // CSR build (rank-based) + weight preconvert
    hist_kernel<<<1024, 256, 0, stream>>>(ei, ew, cw, dout, rank, E);
    wconv<<<640, 256, 0, stream>>>(Wm, Wt);
    scan_kernel<<<1, 1024, 0, stream>>>(cw, offsets, w_in, N);
    scatter_kernel<<<1024, 256, 0, stream>>>(ei, ew, offsets, rank, se, E);

    // ---- layer 0 ----
    colstats_wr<<<64, 256, 0, stream>>>(x, stats2 + 0 * 512, 2, N);
    bn_finalize<<<1, 256, 0, stream>>>(stats2 + 0 * 512, bn0_g, bn0_b, st, 2, N);
    spmm_small<<<(N + 127) / 128, 256, 0, stream>>>(x, se, offsets, agg2, 2, N, 0);
    layer0_fin<<<512, 256, 0, stream>>>(agg2, w_in, st, W0, b0, bufP, sp8 + 0 * 8192, N);

    // ---- 10 mid layers ----
    for (int i = 0; i < 10; i++) {
        bnw<<<64, 256, 0, stream>>>(sp8 + i * 8192, bnm_g + i * 256, bnm_b + i * 256,
                                    Wt + i * 65536, bm + i * 256, Wt2, bias2, N);
        gemm_mfma<<<dim3((N + 127) / 128, 2), 256, 0, stream>>>(bufP, Wt2, bias2, bufQ, N);
        spmm_f16w<<<1024, 256, 0, stream>>>(bufQ, se, offsets, bufP,
                                            sp8 + (i + 1) * 8192, N);
    }

    // ---- last GCN layer (256 -> 16) ----
    bn_finalize16<<<1, 256, 0, stream>>>(sp8 + 10 * 8192, bnm_g + 10 * 256,
                                         bnm_b + 10 * 256, st, N);
    gemm16<<<(N + 15) / 16, 256, 0, stream>>>(bufP, Wl, bl, st, tmp16, N);
    spmm_small<<<(N + 15) / 16, 256, 0, stream>>>(tmp16, se, offsets, hraw, 16, N, 1);

    // ---- final BN -> z (fp16) ----
    colstats_wr<<<64, 256, 0, stream>>>(hraw, stats2 + 1 * 512, 16, N);
    bn_finalize<<<1, 256, 0, stream>>>(stats2 + 1 * 512, bno_g, bno_b, st, 16, N);
    zprep<<<(N * 16 + 255) / 256, 256, 0, stream>>>(hraw, st, Z, N * 16);

    // ---- analytic edge-MLP BN stats + prescaled weights ----
    aggz_spmm<<<(N + 15) / 16, 256, 0, stream>>>(Z, se, offsets, aggz, N);
    zmom<<<256, 256, 0, stream>>>(Z, aggz, dout, cw, MOM, N);
    mlp_ab<<<1, 256, 0, stream>>>(MOM, mW1, mbn_g, mbn_b, mW2, abw, Wp2, E);
    gprep<<<(N + 255) / 256, 256, 0, stream>>>(Z, abw, G, N);

    // ---- edge MLP output (MFMA, bias-in-C, abs-trick, unroll 2) ----
    edge_mfma<<<(E + 255) / 256, 256, 0, stream>>>(Z, ei, Wp2, abw, G, mb2, outp, E);
}